// Round 1
// baseline (412.968 us; speedup 1.0000x reference)
//
#include <hip/hip_runtime.h>
#include <math.h>

// ---------- types ----------
typedef __attribute__((ext_vector_type(4))) float  f32x4;
typedef __attribute__((ext_vector_type(8))) short  bf16x8;   // 8 bf16 in 4 VGPRs
typedef __attribute__((ext_vector_type(4))) short  s16x4;

#define D_MODEL 1024
#define T_LEN   1024
#define H_TOT   64
#define N_HEAD  16
#define DH      64
#define SQUISH_SCALE 1.8137993642342178f   // pi/sqrt(3)

__device__ __forceinline__ float b2f(short u) {
    union { float f; unsigned b; } v; v.b = ((unsigned)(unsigned short)u) << 16; return v.f;
}
__device__ __forceinline__ short f2b(float f) {
    union { float f; unsigned b; } v; v.f = f;
    unsigned r = (v.b + 0x7FFFu + ((v.b >> 16) & 1u)) >> 16;   // RNE
    return (short)r;
}
__device__ __forceinline__ float softplusf(float z) {
    float az = fabsf(z);
    float lp = log1pf(__expf(-az));
    return (z > 0.f) ? z + lp : lp;
}

// ---------- prep kernels ----------
__global__ void convert_x_kernel(const float* __restrict__ src, short* __restrict__ dst) {
    int i = (blockIdx.x * 256 + threadIdx.x) * 4;
    f32x4 v = *(const f32x4*)(src + i);
    s16x4 o;
    o.x = f2b(v.x); o.y = f2b(v.y); o.z = f2b(v.z); o.w = f2b(v.w);
    *(s16x4*)(dst + i) = o;
}

// src: R x C fp32 (row-major) -> dst: C x R bf16 (row-major), scaled
__global__ __launch_bounds__(256) void transpose_convert_kernel(
    const float* __restrict__ src, int R, int C, short* __restrict__ dst, float scale) {
    __shared__ float tile[64][65];
    int c0 = blockIdx.x * 64, r0 = blockIdx.y * 64;
    int tid = threadIdx.x;
    #pragma unroll
    for (int it = 0; it < 16; ++it) {
        int lin = it * 256 + tid;
        int r = lin >> 6, c = lin & 63;
        tile[r][c] = src[(size_t)(r0 + r) * C + c0 + c];
    }
    __syncthreads();
    #pragma unroll
    for (int it = 0; it < 16; ++it) {
        int lin = it * 256 + tid;
        int cc = lin >> 6, rr = lin & 63;
        dst[(size_t)(c0 + cc) * R + r0 + rr] = f2b(tile[rr][cc] * scale);
    }
}

__global__ void bias_setup_kernel(const float* __restrict__ bQ, const float* __restrict__ bK,
                                  const float* __restrict__ bV, const float* __restrict__ bO,
                                  float* __restrict__ biasQKV, float* __restrict__ bias_mean) {
    int i = blockIdx.x * 256 + threadIdx.x;
    if (i < 4096)      biasQKV[i] = bQ[i];
    else if (i < 5120) biasQKV[i] = bK[i - 4096];
    else if (i < 6144) biasQKV[i] = bV[i - 5120];
    else if (i < 7168) {
        int c = i - 6144;
        bias_mean[c] = 0.25f * (bO[c] + bO[1024 + c] + bO[2048 + c] + bO[3072 + c]);
    }
}

// ---------- generic bf16 GEMM: C = A(MxK) * BT(NxK)^T + bias ----------
// 128x128 tile, BK=64, 4 waves (2x2), each wave 64x64 via 4x4 16x16x32 MFMA frags.
__global__ __launch_bounds__(256) void gemm_bt_kernel(
    const short* __restrict__ A, const short* __restrict__ BT,
    const float* __restrict__ bias, float* __restrict__ outF, short* __restrict__ outB,
    int M, int N, int K) {
    __shared__ short lA[128][64];
    __shared__ short lB[128][64];
    const int tid = threadIdx.x;
    const int lane = tid & 63, wave = tid >> 6;
    const int l15 = lane & 15, l4 = lane >> 4;
    const int wr = wave >> 1, wc = wave & 1;
    const int n0 = blockIdx.x * 128, m0 = blockIdx.y * 128;

    f32x4 acc[4][4];
    const f32x4 fz = {0.f, 0.f, 0.f, 0.f};
    #pragma unroll
    for (int m = 0; m < 4; ++m)
        #pragma unroll
        for (int n = 0; n < 4; ++n) acc[m][n] = fz;

    for (int k0 = 0; k0 < K; k0 += 64) {
        __syncthreads();
        #pragma unroll
        for (int it = 0; it < 4; ++it) {
            int lin = it * 256 + tid;
            int r = lin >> 3, c = lin & 7;
            bf16x8 va = *(const bf16x8*)(A + (size_t)(m0 + r) * K + k0 + c * 8);
            *(bf16x8*)&lA[r][(c ^ (r & 7)) << 3] = va;
            bf16x8 vb = *(const bf16x8*)(BT + (size_t)(n0 + r) * K + k0 + c * 8);
            *(bf16x8*)&lB[r][(c ^ (r & 7)) << 3] = vb;
        }
        __syncthreads();
        #pragma unroll
        for (int kk = 0; kk < 2; ++kk) {
            bf16x8 af[4], bf_[4];
            #pragma unroll
            for (int m = 0; m < 4; ++m) {
                int row = wr * 64 + m * 16 + l15;
                int ch = (kk * 4 + l4) ^ (row & 7);
                af[m] = *(const bf16x8*)&lA[row][ch << 3];
            }
            #pragma unroll
            for (int n = 0; n < 4; ++n) {
                int row = wc * 64 + n * 16 + l15;
                int ch = (kk * 4 + l4) ^ (row & 7);
                bf_[n] = *(const bf16x8*)&lB[row][ch << 3];
            }
            #pragma unroll
            for (int m = 0; m < 4; ++m)
                #pragma unroll
                for (int n = 0; n < 4; ++n)
                    acc[m][n] = __builtin_amdgcn_mfma_f32_16x16x32_bf16(af[m], bf_[n], acc[m][n], 0, 0, 0);
        }
    }
    #pragma unroll
    for (int m = 0; m < 4; ++m)
        #pragma unroll
        for (int n = 0; n < 4; ++n)
            #pragma unroll
            for (int r = 0; r < 4; ++r) {
                int row = m0 + wr * 64 + m * 16 + l4 * 4 + r;
                int col = n0 + wc * 64 + n * 16 + l15;
                float v = acc[m][n][r] + bias[col];
                if (outF) outF[(size_t)row * N + col] = v;
                else      outB[(size_t)row * N + col] = f2b(v);
            }
}

// ---------- RoPE (in-place on bf16 QKV) + key_self scale ----------
// grid (T, 20), block 128. heads 0..63 = Q, 64..79 = K (writes ksr = ATTNSCALE*rsqrt(|k|^2)).
__global__ __launch_bounds__(128) void rope_qk_kernel(short* __restrict__ QKVb, float* __restrict__ ksr) {
    int t = blockIdx.x;
    int hl = threadIdx.x >> 5;
    int j  = threadIdx.x & 31;
    int head = blockIdx.y * 4 + hl;
    short* p;
    if (head < 64) p = QKVb + (size_t)t * 6144 + head * 64;
    else           p = QKVb + (size_t)t * 6144 + 4096 + (head - 64) * 64;
    float x1 = b2f(p[2 * j]), x2 = b2f(p[2 * j + 1]);
    float freq = (float)t * __builtin_exp2f(-(float)j * 0.41524101186092033f); // 10000^(-j/32)
    float sn, cs;
    sincosf(freq, &sn, &cs);
    float o1 = x1 * cs - x2 * sn;
    float o2 = x1 * sn + x2 * cs;
    p[j]      = f2b(o1);
    p[32 + j] = f2b(o2);
    if (head >= 64) {
        float ss = o1 * o1 + o2 * o2;
        #pragma unroll
        for (int off = 16; off; off >>= 1) ss += __shfl_xor(ss, off, 32);
        if (j == 0) ksr[(head - 64) * 1024 + t] = 0.125f * rsqrtf(fmaxf(ss, 1e-6f));
    }
}

// ---------- V transpose: QKV V-region (T x 16 x 64) -> Vt (16 x 64 x T) bf16 ----------
__global__ __launch_bounds__(256) void v_transpose_kernel(const short* __restrict__ QKVb, short* __restrict__ Vtb) {
    __shared__ short tile[64][72];
    int h = blockIdx.x, t0 = blockIdx.y * 64;
    int tid = threadIdx.x;
    #pragma unroll
    for (int it = 0; it < 16; ++it) {
        int lin = it * 256 + tid;
        int r = lin >> 6, d = lin & 63;
        tile[r][d] = QKVb[(size_t)(t0 + r) * 6144 + 5120 + h * 64 + d];
    }
    __syncthreads();
    #pragma unroll
    for (int it = 0; it < 16; ++it) {
        int lin = it * 256 + tid;
        int d = lin >> 6, c = lin & 63;
        Vtb[(size_t)(h * 64 + d) * 1024 + t0 + c] = tile[c][d];
    }
}

// ---------- attention ----------
// grid (64 heads, 8 q-tiles of 128), block 256 (4 waves, 32 q-rows each).
__global__ __launch_bounds__(256) void attn_kernel(
    const short* __restrict__ QKVb, const short* __restrict__ Vtb,
    const float* __restrict__ ksr, const float* __restrict__ sinks,
    const float* __restrict__ vnulls, short* __restrict__ Ob) {
    __shared__ short lK[64][64];
    __shared__ short lV[64][64];
    __shared__ float lks[64];
    __shared__ float lvn[64];
    __shared__ short lP[4][32][64];

    const int tid = threadIdx.x;
    const int lane = tid & 63, wave = tid >> 6;
    const int l15 = lane & 15, l4 = lane >> 4;
    const int h = blockIdx.x, qt = blockIdx.y;
    const int h16 = h & 15;
    const int t0 = qt * 128;
    const float sink = sinks[h];
    if (tid < 64) lvn[tid] = vnulls[h * 64 + tid];

    // Q fragments (held in registers for all key tiles)
    bf16x8 aq[2][2];
    #pragma unroll
    for (int m = 0; m < 2; ++m)
        #pragma unroll
        for (int kk = 0; kk < 2; ++kk) {
            int t = t0 + wave * 32 + m * 16 + l15;
            aq[m][kk] = *(const bf16x8*)(QKVb + (size_t)t * 6144 + h * 64 + kk * 32 + l4 * 8);
        }

    const f32x4 fz = {0.f, 0.f, 0.f, 0.f};
    f32x4 acc_o[2][4];
    float tot[2][4];
    #pragma unroll
    for (int m = 0; m < 2; ++m)
        #pragma unroll
        for (int n = 0; n < 4; ++n) acc_o[m][n] = fz;
    #pragma unroll
    for (int m = 0; m < 2; ++m)
        #pragma unroll
        for (int r = 0; r < 4; ++r) tot[m][r] = 0.f;

    const int nkt = 2 * qt + 2;
    for (int kt = 0; kt < nkt; ++kt) {
        int s0 = kt * 64;
        __syncthreads();
        #pragma unroll
        for (int it = 0; it < 2; ++it) {
            int lin = it * 256 + tid;
            int r = lin >> 3, c = lin & 7;
            bf16x8 vk = *(const bf16x8*)(QKVb + (size_t)(s0 + r) * 6144 + 4096 + h16 * 64 + c * 8);
            *(bf16x8*)&lK[r][(c ^ (r & 7)) << 3] = vk;
            bf16x8 vv = *(const bf16x8*)(Vtb + (size_t)(h16 * 64 + r) * 1024 + s0 + c * 8);
            *(bf16x8*)&lV[r][(c ^ (r & 7)) << 3] = vv;
        }
        if (tid < 64) lks[tid] = ksr[h16 * 1024 + s0 + tid];
        __syncthreads();

        // QK^T
        f32x4 accs[2][4];
        #pragma unroll
        for (int m = 0; m < 2; ++m)
            #pragma unroll
            for (int n = 0; n < 4; ++n) accs[m][n] = fz;
        #pragma unroll
        for (int kk = 0; kk < 2; ++kk) {
            bf16x8 bk[4];
            #pragma unroll
            for (int n = 0; n < 4; ++n) {
                int row = n * 16 + l15;
                int ch = (kk * 4 + l4) ^ (row & 7);
                bk[n] = *(const bf16x8*)&lK[row][ch << 3];
            }
            #pragma unroll
            for (int m = 0; m < 2; ++m)
                #pragma unroll
                for (int n = 0; n < 4; ++n)
                    accs[m][n] = __builtin_amdgcn_mfma_f32_16x16x32_bf16(aq[m][kk], bk[n], accs[m][n], 0, 0, 0);
        }

        // weights: softplus -> causal -> SiLU-gate -> sink threshold; accumulate totals; P->LDS
        #pragma unroll
        for (int m = 0; m < 2; ++m)
            #pragma unroll
            for (int n = 0; n < 4; ++n) {
                int scol = s0 + n * 16 + l15;
                float kscale = lks[n * 16 + l15];
                #pragma unroll
                for (int r = 0; r < 4; ++r) {
                    int trow = t0 + wave * 32 + m * 16 + l4 * 4 + r;
                    float z = accs[m][n][r] * kscale;
                    float w = softplusf(z);
                    w = (scol <= trow) ? w : 0.f;
                    w = __fdividef(w, 1.f + __expf(-SQUISH_SCALE * w));
                    if (w < sink) w = 0.f;
                    tot[m][r] += w;
                    int prow = m * 16 + l4 * 4 + r;
                    int pcol = n * 16 + l15;
                    lP[wave][prow][((((pcol >> 3) ^ (prow & 7)) << 3) | (pcol & 7))] = f2b(w);
                }
            }

        // PV (per-wave private lP region; wave-internal ordering via waitcnt)
        #pragma unroll
        for (int kk = 0; kk < 2; ++kk) {
            bf16x8 ap[2], bv[4];
            #pragma unroll
            for (int m = 0; m < 2; ++m) {
                int row = m * 16 + l15;
                int ch = (kk * 4 + l4) ^ (row & 7);
                ap[m] = *(const bf16x8*)&lP[wave][row][ch << 3];
            }
            #pragma unroll
            for (int n = 0; n < 4; ++n) {
                int row = n * 16 + l15;
                int ch = (kk * 4 + l4) ^ (row & 7);
                bv[n] = *(const bf16x8*)&lV[row][ch << 3];
            }
            #pragma unroll
            for (int m = 0; m < 2; ++m)
                #pragma unroll
                for (int n = 0; n < 4; ++n)
                    acc_o[m][n] = __builtin_amdgcn_mfma_f32_16x16x32_bf16(ap[m], bv[n], acc_o[m][n], 0, 0, 0);
        }
    }

    // reduce row totals across the 16 lanes sharing a row
    #pragma unroll
    for (int m = 0; m < 2; ++m)
        #pragma unroll
        for (int r = 0; r < 4; ++r) {
            float s = tot[m][r];
            #pragma unroll
            for (int off = 8; off; off >>= 1) s += __shfl_xor(s, off, 16);
            tot[m][r] = s;
        }

    // epilogue: out = (acc + sink*vnull) / total
    #pragma unroll
    for (int m = 0; m < 2; ++m)
        #pragma unroll
        for (int r = 0; r < 4; ++r) {
            float inv = 1.f / (tot[m][r] + sink + 1e-6f);
            int trow = t0 + wave * 32 + m * 16 + l4 * 4 + r;
            #pragma unroll
            for (int n = 0; n < 4; ++n) {
                int d = n * 16 + l15;
                float val = (acc_o[m][n][r] + sink * lvn[d]) * inv;
                Ob[(size_t)trow * 4096 + h * 64 + d] = f2b(val);
            }
        }
}

// ---------- launch ----------
extern "C" void kernel_launch(void* const* d_in, const int* in_sizes, int n_in,
                              void* d_out, int out_size, void* d_ws, size_t ws_size,
                              hipStream_t stream) {
    const float* X        = (const float*)d_in[0];
    const float* W_Q      = (const float*)d_in[1];
    const float* b_Q      = (const float*)d_in[2];
    const float* W_K      = (const float*)d_in[3];
    const float* b_K      = (const float*)d_in[4];
    const float* W_V      = (const float*)d_in[5];
    const float* b_V      = (const float*)d_in[6];
    const float* sinks    = (const float*)d_in[7];
    const float* v_nulls  = (const float*)d_in[8];
    const float* W_O      = (const float*)d_in[9];
    const float* W_O_bias = (const float*)d_in[10];
    float* out = (float*)d_out;
    char* ws = (char*)d_ws;

    short* Xb        = (short*)(ws + 0);          //  2 MB  (1024x1024)
    short* WbT       = (short*)(ws + 2097152);    // 12 MB  (6144x1024)
    short* WoT       = (short*)(ws + 14680064);   //  8 MB  (1024x4096), pre-scaled 0.25
    short* QKVb      = (short*)(ws + 23068672);   // 12 MB  (1024x6144)
    short* Vtb       = (short*)(ws + 35651584);   //  2 MB  (16x64x1024)
    short* Ob        = (short*)(ws + 37748736);   //  8 MB  (1024x4096)
    float* ksr       = (float*)(ws + 46137344);   // 64 KB  (16x1024)
    float* biasQKV   = (float*)(ws + 46202880);   // 24 KB
    float* bias_mean = (float*)(ws + 46227456);   //  4 KB

    convert_x_kernel<<<1024, 256, 0, stream>>>(X, Xb);
    transpose_convert_kernel<<<dim3(64, 16), 256, 0, stream>>>(W_Q, 1024, 4096, WbT, 1.f);
    transpose_convert_kernel<<<dim3(16, 16), 256, 0, stream>>>(W_K, 1024, 1024, WbT + 4096 * 1024, 1.f);
    transpose_convert_kernel<<<dim3(16, 16), 256, 0, stream>>>(W_V, 1024, 1024, WbT + 5120 * 1024, 1.f);
    transpose_convert_kernel<<<dim3(16, 64), 256, 0, stream>>>(W_O, 4096, 1024, WoT, 0.25f);
    bias_setup_kernel<<<28, 256, 0, stream>>>(b_Q, b_K, b_V, W_O_bias, biasQKV, bias_mean);

    gemm_bt_kernel<<<dim3(48, 8), 256, 0, stream>>>(Xb, WbT, biasQKV, nullptr, QKVb, 1024, 6144, 1024);
    rope_qk_kernel<<<dim3(1024, 20), 128, 0, stream>>>(QKVb, ksr);
    v_transpose_kernel<<<dim3(16, 16), 256, 0, stream>>>(QKVb, Vtb);
    attn_kernel<<<dim3(64, 8), 256, 0, stream>>>(QKVb, Vtb, ksr, sinks, v_nulls, Ob);
    gemm_bt_kernel<<<dim3(8, 8), 256, 0, stream>>>(Ob, WoT, bias_mean, out, nullptr, 1024, 1024, 4096);
}

// Round 2
// 240.103 us; speedup vs baseline: 1.7200x; 1.7200x over previous
//
#include <hip/hip_runtime.h>
#include <math.h>

// ---------- types ----------
typedef __attribute__((ext_vector_type(4))) float  f32x4;
typedef __attribute__((ext_vector_type(8))) short  bf16x8;   // 8 bf16 in 4 VGPRs
typedef __attribute__((ext_vector_type(4))) short  s16x4;

#define D_MODEL 1024
#define T_LEN   1024
#define H_TOT   64
#define N_HEAD  16
#define DH      64
#define SQUISH_SCALE 1.8137993642342178f   // pi/sqrt(3)

__device__ __forceinline__ float b2f(short u) {
    union { float f; unsigned b; } v; v.b = ((unsigned)(unsigned short)u) << 16; return v.f;
}
__device__ __forceinline__ short f2b(float f) {
    union { float f; unsigned b; } v; v.f = f;
    unsigned r = (v.b + 0x7FFFu + ((v.b >> 16) & 1u)) >> 16;   // RNE
    return (short)r;
}

// ---------- prep kernels ----------
__global__ void convert_x_kernel(const float* __restrict__ src, short* __restrict__ dst) {
    int i = (blockIdx.x * 256 + threadIdx.x) * 4;
    f32x4 v = *(const f32x4*)(src + i);
    s16x4 o;
    o.x = f2b(v.x); o.y = f2b(v.y); o.z = f2b(v.z); o.w = f2b(v.w);
    *(s16x4*)(dst + i) = o;
}

// src: R x C fp32 (row-major) -> dst: C x R bf16 (row-major), scaled
__global__ __launch_bounds__(256) void transpose_convert_kernel(
    const float* __restrict__ src, int R, int C, short* __restrict__ dst, float scale) {
    __shared__ float tile[64][65];
    int c0 = blockIdx.x * 64, r0 = blockIdx.y * 64;
    int tid = threadIdx.x;
    #pragma unroll
    for (int it = 0; it < 16; ++it) {
        int lin = it * 256 + tid;
        int r = lin >> 6, c = lin & 63;
        tile[r][c] = src[(size_t)(r0 + r) * C + c0 + c];
    }
    __syncthreads();
    #pragma unroll
    for (int it = 0; it < 16; ++it) {
        int lin = it * 256 + tid;
        int cc = lin >> 6, rr = lin & 63;
        dst[(size_t)(c0 + cc) * R + r0 + rr] = f2b(tile[rr][cc] * scale);
    }
}

__global__ void bias_setup_kernel(const float* __restrict__ bQ, const float* __restrict__ bK,
                                  const float* __restrict__ bV, const float* __restrict__ bO,
                                  float* __restrict__ biasQKV, float* __restrict__ bias_mean) {
    int i = blockIdx.x * 256 + threadIdx.x;
    if (i < 4096)      biasQKV[i] = bQ[i];
    else if (i < 5120) biasQKV[i] = bK[i - 4096];
    else if (i < 6144) biasQKV[i] = bV[i - 5120];
    else if (i < 7168) {
        int c = i - 6144;
        bias_mean[c] = 0.25f * (bO[c] + bO[1024 + c] + bO[2048 + c] + bO[3072 + c]);
    }
}

// ---------- bf16 GEMM 128x128: C = A(MxK) * BT(NxK)^T + bias -> bf16 out ----------
__global__ __launch_bounds__(256) void gemm_bt_kernel(
    const short* __restrict__ A, const short* __restrict__ BT,
    const float* __restrict__ bias, short* __restrict__ outB,
    int M, int N, int K) {
    __shared__ short lA[128][64];
    __shared__ short lB[128][64];
    const int tid = threadIdx.x;
    const int lane = tid & 63, wave = tid >> 6;
    const int l15 = lane & 15, l4 = lane >> 4;
    const int wr = wave >> 1, wc = wave & 1;
    const int n0 = blockIdx.x * 128, m0 = blockIdx.y * 128;

    f32x4 acc[4][4];
    const f32x4 fz = {0.f, 0.f, 0.f, 0.f};
    #pragma unroll
    for (int m = 0; m < 4; ++m)
        #pragma unroll
        for (int n = 0; n < 4; ++n) acc[m][n] = fz;

    for (int k0 = 0; k0 < K; k0 += 64) {
        __syncthreads();
        #pragma unroll
        for (int it = 0; it < 4; ++it) {
            int lin = it * 256 + tid;
            int r = lin >> 3, c = lin & 7;
            bf16x8 va = *(const bf16x8*)(A + (size_t)(m0 + r) * K + k0 + c * 8);
            *(bf16x8*)&lA[r][(c ^ (r & 7)) << 3] = va;
            bf16x8 vb = *(const bf16x8*)(BT + (size_t)(n0 + r) * K + k0 + c * 8);
            *(bf16x8*)&lB[r][(c ^ (r & 7)) << 3] = vb;
        }
        __syncthreads();
        #pragma unroll
        for (int kk = 0; kk < 2; ++kk) {
            bf16x8 af[4], bf_[4];
            #pragma unroll
            for (int m = 0; m < 4; ++m) {
                int row = wr * 64 + m * 16 + l15;
                int ch = (kk * 4 + l4) ^ (row & 7);
                af[m] = *(const bf16x8*)&lA[row][ch << 3];
            }
            #pragma unroll
            for (int n = 0; n < 4; ++n) {
                int row = wc * 64 + n * 16 + l15;
                int ch = (kk * 4 + l4) ^ (row & 7);
                bf_[n] = *(const bf16x8*)&lB[row][ch << 3];
            }
            #pragma unroll
            for (int m = 0; m < 4; ++m)
                #pragma unroll
                for (int n = 0; n < 4; ++n)
                    acc[m][n] = __builtin_amdgcn_mfma_f32_16x16x32_bf16(af[m], bf_[n], acc[m][n], 0, 0, 0);
        }
    }
    #pragma unroll
    for (int m = 0; m < 4; ++m)
        #pragma unroll
        for (int n = 0; n < 4; ++n)
            #pragma unroll
            for (int r = 0; r < 4; ++r) {
                int row = m0 + wr * 64 + m * 16 + l4 * 4 + r;
                int col = n0 + wc * 64 + n * 16 + l15;
                outB[(size_t)row * N + col] = f2b(acc[m][n][r] + bias[col]);
            }
}

// ---------- bf16 GEMM 64x64 tile (for M=N=1024, K=4096 out-proj; 256 blocks) ----------
__global__ __launch_bounds__(256) void gemm_bt64_kernel(
    const short* __restrict__ A, const short* __restrict__ BT,
    const float* __restrict__ bias, float* __restrict__ outF,
    int M, int N, int K) {
    __shared__ short lA[64][64];
    __shared__ short lB[64][64];
    const int tid = threadIdx.x;
    const int lane = tid & 63, wave = tid >> 6;
    const int l15 = lane & 15, l4 = lane >> 4;
    const int wr = wave >> 1, wc = wave & 1;
    const int n0 = blockIdx.x * 64, m0 = blockIdx.y * 64;

    f32x4 acc[2][2];
    const f32x4 fz = {0.f, 0.f, 0.f, 0.f};
    #pragma unroll
    for (int m = 0; m < 2; ++m)
        #pragma unroll
        for (int n = 0; n < 2; ++n) acc[m][n] = fz;

    for (int k0 = 0; k0 < K; k0 += 64) {
        __syncthreads();
        #pragma unroll
        for (int it = 0; it < 2; ++it) {
            int lin = it * 256 + tid;
            int r = lin >> 3, c = lin & 7;
            bf16x8 va = *(const bf16x8*)(A + (size_t)(m0 + r) * K + k0 + c * 8);
            *(bf16x8*)&lA[r][(c ^ (r & 7)) << 3] = va;
            bf16x8 vb = *(const bf16x8*)(BT + (size_t)(n0 + r) * K + k0 + c * 8);
            *(bf16x8*)&lB[r][(c ^ (r & 7)) << 3] = vb;
        }
        __syncthreads();
        #pragma unroll
        for (int kk = 0; kk < 2; ++kk) {
            bf16x8 af[2], bf_[2];
            #pragma unroll
            for (int m = 0; m < 2; ++m) {
                int row = wr * 32 + m * 16 + l15;
                int ch = (kk * 4 + l4) ^ (row & 7);
                af[m] = *(const bf16x8*)&lA[row][ch << 3];
            }
            #pragma unroll
            for (int n = 0; n < 2; ++n) {
                int row = wc * 32 + n * 16 + l15;
                int ch = (kk * 4 + l4) ^ (row & 7);
                bf_[n] = *(const bf16x8*)&lB[row][ch << 3];
            }
            #pragma unroll
            for (int m = 0; m < 2; ++m)
                #pragma unroll
                for (int n = 0; n < 2; ++n)
                    acc[m][n] = __builtin_amdgcn_mfma_f32_16x16x32_bf16(af[m], bf_[n], acc[m][n], 0, 0, 0);
        }
    }
    #pragma unroll
    for (int m = 0; m < 2; ++m)
        #pragma unroll
        for (int n = 0; n < 2; ++n)
            #pragma unroll
            for (int r = 0; r < 4; ++r) {
                int row = m0 + wr * 32 + m * 16 + l4 * 4 + r;
                int col = n0 + wc * 32 + n * 16 + l15;
                outF[(size_t)row * N + col] = acc[m][n][r] + bias[col];
            }
}

// ---------- RoPE (in-place, bf16 QKV) + key_self scale; fast hw sin/cos ----------
__global__ __launch_bounds__(128) void rope_qk_kernel(short* __restrict__ QKVb, float* __restrict__ ksr) {
    int t = blockIdx.x;
    int hl = threadIdx.x >> 5;
    int j  = threadIdx.x & 31;
    int head = blockIdx.y * 4 + hl;
    short* p;
    if (head < 64) p = QKVb + (size_t)t * 6144 + head * 64;
    else           p = QKVb + (size_t)t * 6144 + 4096 + (head - 64) * 64;
    float x1 = b2f(p[2 * j]), x2 = b2f(p[2 * j + 1]);
    float freq = (float)t * __builtin_exp2f(-(float)j * 0.41524101186092033f); // 10000^(-j/32)
    float sn = __sinf(freq), cs = __cosf(freq);
    float o1 = x1 * cs - x2 * sn;
    float o2 = x1 * sn + x2 * cs;
    p[j]      = f2b(o1);
    p[32 + j] = f2b(o2);
    if (head >= 64) {
        float ss = o1 * o1 + o2 * o2;
        #pragma unroll
        for (int off = 16; off; off >>= 1) ss += __shfl_xor(ss, off, 32);
        if (j == 0) ksr[(head - 64) * 1024 + t] = 0.125f * rsqrtf(fmaxf(ss, 1e-6f));
    }
}

// ---------- V transpose: QKV V-region (T x 16 x 64) -> Vt (16 x 64 x T) bf16 ----------
__global__ __launch_bounds__(256) void v_transpose_kernel(const short* __restrict__ QKVb, short* __restrict__ Vtb) {
    __shared__ short tile[64][72];
    int h = blockIdx.x, t0 = blockIdx.y * 64;
    int tid = threadIdx.x;
    #pragma unroll
    for (int it = 0; it < 16; ++it) {
        int lin = it * 256 + tid;
        int r = lin >> 6, d = lin & 63;
        tile[r][d] = QKVb[(size_t)(t0 + r) * 6144 + 5120 + h * 64 + d];
    }
    __syncthreads();
    #pragma unroll
    for (int it = 0; it < 16; ++it) {
        int lin = it * 256 + tid;
        int d = lin >> 6, c = lin & 63;
        Vtb[(size_t)(h * 64 + d) * 1024 + t0 + c] = tile[c][d];
    }
}

// ---------- attention ----------
// grid (64 heads, 8 pairs), block 256 (4 waves, 16 q-rows each per 64-row tile).
// Block p processes q-tiles {p, 15-p}: nkt = (p+1) + (16-p) = 17 k-tiles, uniform.
__global__ __launch_bounds__(256) void attn_kernel(
    const short* __restrict__ QKVb, const short* __restrict__ Vtb,
    const float* __restrict__ ksr, const float* __restrict__ sinks,
    const float* __restrict__ vnulls, short* __restrict__ Ob) {
    __shared__ short lK[64][64];
    __shared__ short lV[64][64];
    __shared__ float lks[64];
    __shared__ float lvn[64];
    __shared__ short lP[4][16][64];

    const int tid = threadIdx.x;
    const int lane = tid & 63, wave = tid >> 6;
    const int l15 = lane & 15, l4 = lane >> 4;
    const int h = blockIdx.x, pidx = blockIdx.y;
    const int h16 = h & 15;
    const float sink = sinks[h];
    if (tid < 64) lvn[tid] = vnulls[h * 64 + tid];

    const f32x4 fz = {0.f, 0.f, 0.f, 0.f};

    #pragma unroll
    for (int half = 0; half < 2; ++half) {
        const int qt = half ? (15 - pidx) : pidx;
        const int t0 = qt * 64;

        // Q fragments for this tile (16 rows per wave)
        bf16x8 aq[2];
        #pragma unroll
        for (int kk = 0; kk < 2; ++kk) {
            int t = t0 + wave * 16 + l15;
            aq[kk] = *(const bf16x8*)(QKVb + (size_t)t * 6144 + h * 64 + kk * 32 + l4 * 8);
        }

        f32x4 acc_o[4];
        float tot[4];
        #pragma unroll
        for (int n = 0; n < 4; ++n) acc_o[n] = fz;
        #pragma unroll
        for (int r = 0; r < 4; ++r) tot[r] = 0.f;

        const int nkt = qt + 1;
        for (int kt = 0; kt < nkt; ++kt) {
            int s0 = kt * 64;
            __syncthreads();
            #pragma unroll
            for (int it = 0; it < 2; ++it) {
                int lin = it * 256 + tid;
                int r = lin >> 3, c = lin & 7;
                bf16x8 vk = *(const bf16x8*)(QKVb + (size_t)(s0 + r) * 6144 + 4096 + h16 * 64 + c * 8);
                *(bf16x8*)&lK[r][(c ^ (r & 7)) << 3] = vk;
                bf16x8 vv = *(const bf16x8*)(Vtb + (size_t)(h16 * 64 + r) * 1024 + s0 + c * 8);
                *(bf16x8*)&lV[r][(c ^ (r & 7)) << 3] = vv;
            }
            if (tid < 64) lks[tid] = ksr[h16 * 1024 + s0 + tid];
            __syncthreads();

            // QK^T (16 q-rows x 64 keys per wave)
            f32x4 accs[4];
            #pragma unroll
            for (int n = 0; n < 4; ++n) accs[n] = fz;
            #pragma unroll
            for (int kk = 0; kk < 2; ++kk) {
                bf16x8 bk[4];
                #pragma unroll
                for (int n = 0; n < 4; ++n) {
                    int row = n * 16 + l15;
                    int ch = (kk * 4 + l4) ^ (row & 7);
                    bk[n] = *(const bf16x8*)&lK[row][ch << 3];
                }
                #pragma unroll
                for (int n = 0; n < 4; ++n)
                    accs[n] = __builtin_amdgcn_mfma_f32_16x16x32_bf16(aq[kk], bk[n], accs[n], 0, 0, 0);
            }

            // fast-math weights: softplus -> causal -> SiLU gate -> sink threshold
            #pragma unroll
            for (int n = 0; n < 4; ++n) {
                int scol = s0 + n * 16 + l15;
                float kscale = lks[n * 16 + l15];
                #pragma unroll
                for (int r = 0; r < 4; ++r) {
                    int trow = t0 + wave * 16 + l4 * 4 + r;
                    float z = accs[n][r] * kscale;
                    float e = __expf(-fabsf(z));
                    float w = fmaxf(z, 0.f) + __logf(1.f + e);
                    w = (scol <= trow) ? w : 0.f;
                    float g = __expf(-SQUISH_SCALE * w);
                    w = w * __builtin_amdgcn_rcpf(1.f + g);
                    w = (w >= sink) ? w : 0.f;
                    tot[r] += w;
                    int prow = l4 * 4 + r;
                    int pcol = n * 16 + l15;
                    lP[wave][prow][((((pcol >> 3) ^ (prow & 7)) << 3) | (pcol & 7))] = f2b(w);
                }
            }

            // PV (per-wave private lP region; wave-internal ordering via lgkmcnt)
            #pragma unroll
            for (int kk = 0; kk < 2; ++kk) {
                bf16x8 ap, bv[4];
                {
                    int row = l15;
                    int ch = (kk * 4 + l4) ^ (row & 7);
                    ap = *(const bf16x8*)&lP[wave][row][ch << 3];
                }
                #pragma unroll
                for (int n = 0; n < 4; ++n) {
                    int row = n * 16 + l15;
                    int ch = (kk * 4 + l4) ^ (row & 7);
                    bv[n] = *(const bf16x8*)&lV[row][ch << 3];
                }
                #pragma unroll
                for (int n = 0; n < 4; ++n)
                    acc_o[n] = __builtin_amdgcn_mfma_f32_16x16x32_bf16(ap, bv[n], acc_o[n], 0, 0, 0);
            }
        }

        // reduce row totals across the 16 lanes sharing a row
        #pragma unroll
        for (int r = 0; r < 4; ++r) {
            float s = tot[r];
            #pragma unroll
            for (int off = 8; off; off >>= 1) s += __shfl_xor(s, off, 16);
            tot[r] = s;
        }

        // epilogue: out = (acc + sink*vnull) / total
        #pragma unroll
        for (int r = 0; r < 4; ++r) {
            float inv = __builtin_amdgcn_rcpf(tot[r] + sink + 1e-6f);
            int trow = t0 + wave * 16 + l4 * 4 + r;
            #pragma unroll
            for (int n = 0; n < 4; ++n) {
                int d = n * 16 + l15;
                float val = (acc_o[n][r] + sink * lvn[d]) * inv;
                Ob[(size_t)trow * 4096 + h * 64 + d] = f2b(val);
            }
        }
    }
}

// ---------- launch ----------
extern "C" void kernel_launch(void* const* d_in, const int* in_sizes, int n_in,
                              void* d_out, int out_size, void* d_ws, size_t ws_size,
                              hipStream_t stream) {
    const float* X        = (const float*)d_in[0];
    const float* W_Q      = (const float*)d_in[1];
    const float* b_Q      = (const float*)d_in[2];
    const float* W_K      = (const float*)d_in[3];
    const float* b_K      = (const float*)d_in[4];
    const float* W_V      = (const float*)d_in[5];
    const float* b_V      = (const float*)d_in[6];
    const float* sinks    = (const float*)d_in[7];
    const float* v_nulls  = (const float*)d_in[8];
    const float* W_O      = (const float*)d_in[9];
    const float* W_O_bias = (const float*)d_in[10];
    float* out = (float*)d_out;
    char* ws = (char*)d_ws;

    short* Xb        = (short*)(ws + 0);          //  2 MB  (1024x1024)
    short* WbT       = (short*)(ws + 2097152);    // 12 MB  (6144x1024)
    short* WoT       = (short*)(ws + 14680064);   //  8 MB  (1024x4096), pre-scaled 0.25
    short* QKVb      = (short*)(ws + 23068672);   // 12 MB  (1024x6144)
    short* Vtb       = (short*)(ws + 35651584);   //  2 MB  (16x64x1024)
    short* Ob        = (short*)(ws + 37748736);   //  8 MB  (1024x4096)
    float* ksr       = (float*)(ws + 46137344);   // 64 KB  (16x1024)
    float* biasQKV   = (float*)(ws + 46202880);   // 24 KB
    float* bias_mean = (float*)(ws + 46227456);   //  4 KB

    convert_x_kernel<<<1024, 256, 0, stream>>>(X, Xb);
    transpose_convert_kernel<<<dim3(64, 16), 256, 0, stream>>>(W_Q, 1024, 4096, WbT, 1.f);
    transpose_convert_kernel<<<dim3(16, 16), 256, 0, stream>>>(W_K, 1024, 1024, WbT + 4096 * 1024, 1.f);
    transpose_convert_kernel<<<dim3(16, 16), 256, 0, stream>>>(W_V, 1024, 1024, WbT + 5120 * 1024, 1.f);
    transpose_convert_kernel<<<dim3(16, 64), 256, 0, stream>>>(W_O, 4096, 1024, WoT, 0.25f);
    bias_setup_kernel<<<28, 256, 0, stream>>>(b_Q, b_K, b_V, W_O_bias, biasQKV, bias_mean);

    gemm_bt_kernel<<<dim3(48, 8), 256, 0, stream>>>(Xb, WbT, biasQKV, QKVb, 1024, 6144, 1024);
    rope_qk_kernel<<<dim3(1024, 20), 128, 0, stream>>>(QKVb, ksr);
    v_transpose_kernel<<<dim3(16, 16), 256, 0, stream>>>(QKVb, Vtb);
    attn_kernel<<<dim3(64, 8), 256, 0, stream>>>(QKVb, Vtb, ksr, sinks, v_nulls, Ob);
    gemm_bt64_kernel<<<dim3(16, 16), 256, 0, stream>>>(Ob, WoT, bias_mean, out, 1024, 1024, 4096);
}

// Round 3
// 217.415 us; speedup vs baseline: 1.8994x; 1.1044x over previous
//
#include <hip/hip_runtime.h>
#include <math.h>

// ---------- types ----------
typedef __attribute__((ext_vector_type(4))) float  f32x4;
typedef __attribute__((ext_vector_type(8))) short  bf16x8;   // 8 bf16 in 4 VGPRs
typedef __attribute__((ext_vector_type(4))) short  s16x4;

#define D_MODEL 1024
#define T_LEN   1024
#define H_TOT   64
#define N_HEAD  16
#define DH      64
#define SQUISH_SCALE 1.8137993642342178f   // pi/sqrt(3)

__device__ __forceinline__ float b2f(short u) {
    union { float f; unsigned b; } v; v.b = ((unsigned)(unsigned short)u) << 16; return v.f;
}
__device__ __forceinline__ short f2b(float f) {
    union { float f; unsigned b; } v; v.f = f;
    unsigned r = (v.b + 0x7FFFu + ((v.b >> 16) & 1u)) >> 16;   // RNE
    return (short)r;
}
__device__ __forceinline__ unsigned cvt_pk_bf16(float lo, float hi) {
    unsigned r;
    asm("v_cvt_pk_bf16_f32 %0, %1, %2" : "=v"(r) : "v"(lo), "v"(hi));
    return r;
}
// async global->LDS, 16B per lane; lds base is wave-uniform, HW adds lane*16
__device__ __forceinline__ void gll16(const void* g, void* l) {
    __builtin_amdgcn_global_load_lds((const __attribute__((address_space(1))) void*)g,
                                     (__attribute__((address_space(3))) void*)l, 16, 0, 0);
}

// ---------- prep kernels ----------
__global__ void convert_x_kernel(const float* __restrict__ src, short* __restrict__ dst) {
    int i = (blockIdx.x * 256 + threadIdx.x) * 4;
    f32x4 v = *(const f32x4*)(src + i);
    s16x4 o;
    o.x = f2b(v.x); o.y = f2b(v.y); o.z = f2b(v.z); o.w = f2b(v.w);
    *(s16x4*)(dst + i) = o;
}

// src: R x C fp32 (row-major) -> dst: C x R bf16 (row-major), scaled
__global__ __launch_bounds__(256) void transpose_convert_kernel(
    const float* __restrict__ src, int R, int C, short* __restrict__ dst, float scale) {
    __shared__ float tile[64][65];
    int c0 = blockIdx.x * 64, r0 = blockIdx.y * 64;
    int tid = threadIdx.x;
    #pragma unroll
    for (int it = 0; it < 16; ++it) {
        int lin = it * 256 + tid;
        int r = lin >> 6, c = lin & 63;
        tile[r][c] = src[(size_t)(r0 + r) * C + c0 + c];
    }
    __syncthreads();
    #pragma unroll
    for (int it = 0; it < 16; ++it) {
        int lin = it * 256 + tid;
        int cc = lin >> 6, rr = lin & 63;
        dst[(size_t)(c0 + cc) * R + r0 + rr] = f2b(tile[rr][cc] * scale);
    }
}

__global__ void bias_setup_kernel(const float* __restrict__ bQ, const float* __restrict__ bK,
                                  const float* __restrict__ bV, const float* __restrict__ bO,
                                  float* __restrict__ biasQKV, float* __restrict__ bias_mean) {
    int i = blockIdx.x * 256 + threadIdx.x;
    if (i < 4096)      biasQKV[i] = bQ[i];
    else if (i < 5120) biasQKV[i] = bK[i - 4096];
    else if (i < 6144) biasQKV[i] = bV[i - 5120];
    else if (i < 7168) {
        int c = i - 6144;
        bias_mean[c] = 0.25f * (bO[c] + bO[1024 + c] + bO[2048 + c] + bO[3072 + c]);
    }
}

// out[i] = bias_mean[i % 1024]  (init for split-K atomic accumulation)
__global__ void init_out_kernel(const float* __restrict__ bias_mean, float* __restrict__ out) {
    int i = (blockIdx.x * 256 + threadIdx.x) * 4;
    f32x4 v;
    v.x = bias_mean[(i)     & 1023];
    v.y = bias_mean[(i + 1) & 1023];
    v.z = bias_mean[(i + 2) & 1023];
    v.w = bias_mean[(i + 3) & 1023];
    *(f32x4*)(out + i) = v;
}

// ---------- bf16 GEMM 128x128: C = A(MxK) * BT(NxK)^T + bias -> bf16 out ----------
__global__ __launch_bounds__(256) void gemm_bt_kernel(
    const short* __restrict__ A, const short* __restrict__ BT,
    const float* __restrict__ bias, short* __restrict__ outB,
    int M, int N, int K) {
    __shared__ short lA[128][64];
    __shared__ short lB[128][64];
    const int tid = threadIdx.x;
    const int lane = tid & 63, wave = tid >> 6;
    const int l15 = lane & 15, l4 = lane >> 4;
    const int wr = wave >> 1, wc = wave & 1;
    const int n0 = blockIdx.x * 128, m0 = blockIdx.y * 128;

    f32x4 acc[4][4];
    const f32x4 fz = {0.f, 0.f, 0.f, 0.f};
    #pragma unroll
    for (int m = 0; m < 4; ++m)
        #pragma unroll
        for (int n = 0; n < 4; ++n) acc[m][n] = fz;

    for (int k0 = 0; k0 < K; k0 += 64) {
        __syncthreads();
        #pragma unroll
        for (int it = 0; it < 4; ++it) {
            int lin0 = it * 256 + wave * 64;
            int lin = lin0 + lane;
            int r = lin >> 3, c = (lin & 7) ^ (r & 7);   // pre-swizzled source
            gll16(A  + (size_t)(m0 + r) * K + k0 + c * 8, (char*)lA + lin0 * 16);
            gll16(BT + (size_t)(n0 + r) * K + k0 + c * 8, (char*)lB + lin0 * 16);
        }
        __syncthreads();
        #pragma unroll
        for (int kk = 0; kk < 2; ++kk) {
            bf16x8 af[4], bf_[4];
            #pragma unroll
            for (int m = 0; m < 4; ++m) {
                int row = wr * 64 + m * 16 + l15;
                int ch = (kk * 4 + l4) ^ (row & 7);
                af[m] = *(const bf16x8*)&lA[row][ch << 3];
            }
            #pragma unroll
            for (int n = 0; n < 4; ++n) {
                int row = wc * 64 + n * 16 + l15;
                int ch = (kk * 4 + l4) ^ (row & 7);
                bf_[n] = *(const bf16x8*)&lB[row][ch << 3];
            }
            #pragma unroll
            for (int m = 0; m < 4; ++m)
                #pragma unroll
                for (int n = 0; n < 4; ++n)
                    acc[m][n] = __builtin_amdgcn_mfma_f32_16x16x32_bf16(af[m], bf_[n], acc[m][n], 0, 0, 0);
        }
    }
    #pragma unroll
    for (int m = 0; m < 4; ++m)
        #pragma unroll
        for (int n = 0; n < 4; ++n)
            #pragma unroll
            for (int r = 0; r < 4; ++r) {
                int row = m0 + wr * 64 + m * 16 + l4 * 4 + r;
                int col = n0 + wc * 64 + n * 16 + l15;
                outB[(size_t)row * N + col] = f2b(acc[m][n][r] + bias[col]);
            }
}

// ---------- out-proj: 64x64 tile, split-K=4, fp32 atomic accumulate ----------
__global__ __launch_bounds__(256) void gemm_bt64_splitk_kernel(
    const short* __restrict__ A, const short* __restrict__ BT,
    float* __restrict__ out, int M, int N, int K, int KSLICE) {
    __shared__ short lA[64][64];
    __shared__ short lB[64][64];
    const int tid = threadIdx.x;
    const int lane = tid & 63, wave = tid >> 6;
    const int l15 = lane & 15, l4 = lane >> 4;
    const int wr = wave >> 1, wc = wave & 1;
    const int n0 = blockIdx.x * 64, m0 = blockIdx.y * 64;
    const int kbeg = blockIdx.z * KSLICE, kend = kbeg + KSLICE;

    f32x4 acc[2][2];
    const f32x4 fz = {0.f, 0.f, 0.f, 0.f};
    #pragma unroll
    for (int m = 0; m < 2; ++m)
        #pragma unroll
        for (int n = 0; n < 2; ++n) acc[m][n] = fz;

    for (int k0 = kbeg; k0 < kend; k0 += 64) {
        __syncthreads();
        #pragma unroll
        for (int it = 0; it < 2; ++it) {
            int lin0 = it * 256 + wave * 64;
            int lin = lin0 + lane;
            int r = lin >> 3, c = (lin & 7) ^ (r & 7);
            gll16(A  + (size_t)(m0 + r) * K + k0 + c * 8, (char*)lA + lin0 * 16);
            gll16(BT + (size_t)(n0 + r) * K + k0 + c * 8, (char*)lB + lin0 * 16);
        }
        __syncthreads();
        #pragma unroll
        for (int kk = 0; kk < 2; ++kk) {
            bf16x8 af[2], bf_[2];
            #pragma unroll
            for (int m = 0; m < 2; ++m) {
                int row = wr * 32 + m * 16 + l15;
                int ch = (kk * 4 + l4) ^ (row & 7);
                af[m] = *(const bf16x8*)&lA[row][ch << 3];
            }
            #pragma unroll
            for (int n = 0; n < 2; ++n) {
                int row = wc * 32 + n * 16 + l15;
                int ch = (kk * 4 + l4) ^ (row & 7);
                bf_[n] = *(const bf16x8*)&lB[row][ch << 3];
            }
            #pragma unroll
            for (int m = 0; m < 2; ++m)
                #pragma unroll
                for (int n = 0; n < 2; ++n)
                    acc[m][n] = __builtin_amdgcn_mfma_f32_16x16x32_bf16(af[m], bf_[n], acc[m][n], 0, 0, 0);
        }
    }
    #pragma unroll
    for (int m = 0; m < 2; ++m)
        #pragma unroll
        for (int n = 0; n < 2; ++n)
            #pragma unroll
            for (int r = 0; r < 4; ++r) {
                int row = m0 + wr * 32 + m * 16 + l4 * 4 + r;
                int col = n0 + wc * 32 + n * 16 + l15;
                unsafeAtomicAdd(&out[(size_t)row * N + col], acc[m][n][r]);
            }
}

// ---------- RoPE (in-place, bf16 QKV) + key_self scale; fast hw sin/cos ----------
__global__ __launch_bounds__(128) void rope_qk_kernel(short* __restrict__ QKVb, float* __restrict__ ksr) {
    int t = blockIdx.x;
    int hl = threadIdx.x >> 5;
    int j  = threadIdx.x & 31;
    int head = blockIdx.y * 4 + hl;
    short* p;
    if (head < 64) p = QKVb + (size_t)t * 6144 + head * 64;
    else           p = QKVb + (size_t)t * 6144 + 4096 + (head - 64) * 64;
    float x1 = b2f(p[2 * j]), x2 = b2f(p[2 * j + 1]);
    float freq = (float)t * __builtin_exp2f(-(float)j * 0.41524101186092033f); // 10000^(-j/32)
    float sn = __sinf(freq), cs = __cosf(freq);
    float o1 = x1 * cs - x2 * sn;
    float o2 = x1 * sn + x2 * cs;
    p[j]      = f2b(o1);
    p[32 + j] = f2b(o2);
    if (head >= 64) {
        float ss = o1 * o1 + o2 * o2;
        #pragma unroll
        for (int off = 16; off; off >>= 1) ss += __shfl_xor(ss, off, 32);
        if (j == 0) ksr[(head - 64) * 1024 + t] = 0.125f * rsqrtf(fmaxf(ss, 1e-6f));
    }
}

// ---------- V transpose: QKV V-region (T x 16 x 64) -> Vt (16 x 64 x T) bf16 ----------
__global__ __launch_bounds__(256) void v_transpose_kernel(const short* __restrict__ QKVb, short* __restrict__ Vtb) {
    __shared__ short tile[64][72];
    int h = blockIdx.x, t0 = blockIdx.y * 64;
    int tid = threadIdx.x;
    #pragma unroll
    for (int it = 0; it < 16; ++it) {
        int lin = it * 256 + tid;
        int r = lin >> 6, d = lin & 63;
        tile[r][d] = QKVb[(size_t)(t0 + r) * 6144 + 5120 + h * 64 + d];
    }
    __syncthreads();
    #pragma unroll
    for (int it = 0; it < 16; ++it) {
        int lin = it * 256 + tid;
        int d = lin >> 6, c = lin & 63;
        Vtb[(size_t)(h * 64 + d) * 1024 + t0 + c] = tile[c][d];
    }
}

// ---------- attention ----------
// grid (64 heads, 16 q-tiles of 64 rows; heaviest first), block 256 (4 waves x 16 q-rows).
// Swapped QK^T: accs = mfma(K, Q) -> lane holds q = l15 (uniform), k = l4*4+r per n-block.
__global__ __launch_bounds__(256, 4) void attn_kernel(
    const short* __restrict__ QKVb, const short* __restrict__ Vtb,
    const float* __restrict__ ksr, const float* __restrict__ sinks,
    const float* __restrict__ vnulls, short* __restrict__ Ob) {
    __shared__ short lK[64][64];
    __shared__ short lV[64][64];
    __shared__ float lks[64];
    __shared__ float lvn[64];
    __shared__ short lP[4][16][64];

    const int tid = threadIdx.x;
    const int lane = tid & 63, wave = tid >> 6;
    const int l15 = lane & 15, l4 = lane >> 4;
    const int h = blockIdx.x;
    const int qt = 15 - blockIdx.y;          // heavy tiles dispatch first
    const int h16 = h & 15;
    const int t0 = qt * 64;
    const float sink = sinks[h];
    if (tid < 64) lvn[tid] = vnulls[h * 64 + tid];

    // Q fragments (B-operand: lane holds q = l15, d-slice = kk*32 + l4*8)
    const int q_abs = t0 + wave * 16 + l15;
    bf16x8 aq[2];
    #pragma unroll
    for (int kk = 0; kk < 2; ++kk)
        aq[kk] = *(const bf16x8*)(QKVb + (size_t)q_abs * 6144 + h * 64 + kk * 32 + l4 * 8);

    const f32x4 fz = {0.f, 0.f, 0.f, 0.f};
    f32x4 acc_o[4];
    #pragma unroll
    for (int n = 0; n < 4; ++n) acc_o[n] = fz;
    float tot = 0.f;

    const int nkt = qt + 1;
    for (int kt = 0; kt < nkt; ++kt) {
        int s0 = kt * 64;
        __syncthreads();
        #pragma unroll
        for (int it = 0; it < 2; ++it) {
            int lin0 = it * 256 + wave * 64;
            int lin = lin0 + lane;
            int r = lin >> 3, c = (lin & 7) ^ (r & 7);   // pre-swizzled source
            gll16(QKVb + (size_t)(s0 + r) * 6144 + 4096 + h16 * 64 + c * 8, (char*)lK + lin0 * 16);
            gll16(Vtb + (size_t)(h16 * 64 + r) * 1024 + s0 + c * 8,          (char*)lV + lin0 * 16);
        }
        if (tid < 64) lks[tid] = ksr[h16 * 1024 + s0 + tid];
        __syncthreads();

        // QK^T swapped: A = K (rows = keys), B = Q (cols = q)
        f32x4 accs[4];
        #pragma unroll
        for (int n = 0; n < 4; ++n) accs[n] = fz;
        #pragma unroll
        for (int kk = 0; kk < 2; ++kk) {
            bf16x8 bk[4];
            #pragma unroll
            for (int n = 0; n < 4; ++n) {
                int row = n * 16 + l15;
                int ch = (kk * 4 + l4) ^ (row & 7);
                bk[n] = *(const bf16x8*)&lK[row][ch << 3];
            }
            #pragma unroll
            for (int n = 0; n < 4; ++n)
                accs[n] = __builtin_amdgcn_mfma_f32_16x16x32_bf16(bk[n], aq[kk], accs[n], 0, 0, 0);
        }

        // weights: softplus -> causal -> SiLU gate -> sink threshold; pack to lP (P[q][k], swizzled)
        #pragma unroll
        for (int n = 0; n < 4; ++n) {
            f32x4 ksv = *(const f32x4*)&lks[n * 16 + l4 * 4];
            float w4[4];
            #pragma unroll
            for (int r = 0; r < 4; ++r) {
                int k_abs = s0 + n * 16 + l4 * 4 + r;
                float z = accs[n][r] * ksv[r];
                float e = __expf(-fabsf(z));
                float w = fmaxf(z, 0.f) + __logf(1.f + e);
                w = (k_abs <= q_abs) ? w : 0.f;
                float g = __expf(-SQUISH_SCALE * w);
                w = w * __builtin_amdgcn_rcpf(1.f + g);
                w = (w >= sink) ? w : 0.f;
                tot += w;
                w4[r] = w;
            }
            unsigned pa = cvt_pk_bf16(w4[0], w4[1]);
            unsigned pb = cvt_pk_bf16(w4[2], w4[3]);
            int ch = (2 * n + (l4 >> 1)) ^ (l15 & 7);
            uint2 val; val.x = pa; val.y = pb;
            *(uint2*)&lP[wave][l15][ch * 8 + (l4 & 1) * 4] = val;
        }

        // PV: A = P (rows = q), B = V^T (cols = d); per-wave private lP (lgkmcnt orders it)
        #pragma unroll
        for (int kk = 0; kk < 2; ++kk) {
            bf16x8 ap = *(const bf16x8*)&lP[wave][l15][((kk * 4 + l4) ^ (l15 & 7)) << 3];
            bf16x8 bv[4];
            #pragma unroll
            for (int n = 0; n < 4; ++n) {
                int row = n * 16 + l15;
                int ch = (kk * 4 + l4) ^ (row & 7);
                bv[n] = *(const bf16x8*)&lV[row][ch << 3];
            }
            #pragma unroll
            for (int n = 0; n < 4; ++n)
                acc_o[n] = __builtin_amdgcn_mfma_f32_16x16x32_bf16(ap, bv[n], acc_o[n], 0, 0, 0);
        }
    }

    // row totals: lane's tot covers its 16 k-columns; sum across the 4 l4-groups
    tot += __shfl_xor(tot, 16, 64);
    tot += __shfl_xor(tot, 32, 64);
    float tq[4];
    #pragma unroll
    for (int r = 0; r < 4; ++r) tq[r] = __shfl(tot, l4 * 4 + r, 64);

    // epilogue: out = (acc + sink*vnull) / total
    #pragma unroll
    for (int r = 0; r < 4; ++r) {
        float inv = __builtin_amdgcn_rcpf(tq[r] + sink + 1e-6f);
        int trow = t0 + wave * 16 + l4 * 4 + r;
        #pragma unroll
        for (int n = 0; n < 4; ++n) {
            int d = n * 16 + l15;
            float val = (acc_o[n][r] + sink * lvn[d]) * inv;
            Ob[(size_t)trow * 4096 + h * 64 + d] = f2b(val);
        }
    }
}

// ---------- launch ----------
extern "C" void kernel_launch(void* const* d_in, const int* in_sizes, int n_in,
                              void* d_out, int out_size, void* d_ws, size_t ws_size,
                              hipStream_t stream) {
    const float* X        = (const float*)d_in[0];
    const float* W_Q      = (const float*)d_in[1];
    const float* b_Q      = (const float*)d_in[2];
    const float* W_K      = (const float*)d_in[3];
    const float* b_K      = (const float*)d_in[4];
    const float* W_V      = (const float*)d_in[5];
    const float* b_V      = (const float*)d_in[6];
    const float* sinks    = (const float*)d_in[7];
    const float* v_nulls  = (const float*)d_in[8];
    const float* W_O      = (const float*)d_in[9];
    const float* W_O_bias = (const float*)d_in[10];
    float* out = (float*)d_out;
    char* ws = (char*)d_ws;

    short* Xb        = (short*)(ws + 0);          //  2 MB  (1024x1024)
    short* WbT       = (short*)(ws + 2097152);    // 12 MB  (6144x1024)
    short* WoT       = (short*)(ws + 14680064);   //  8 MB  (1024x4096), pre-scaled 0.25
    short* QKVb      = (short*)(ws + 23068672);   // 12 MB  (1024x6144)
    short* Vtb       = (short*)(ws + 35651584);   //  2 MB  (16x64x1024)
    short* Ob        = (short*)(ws + 37748736);   //  8 MB  (1024x4096)
    float* ksr       = (float*)(ws + 46137344);   // 64 KB  (16x1024)
    float* biasQKV   = (float*)(ws + 46202880);   // 24 KB
    float* bias_mean = (float*)(ws + 46227456);   //  4 KB

    convert_x_kernel<<<1024, 256, 0, stream>>>(X, Xb);
    transpose_convert_kernel<<<dim3(64, 16), 256, 0, stream>>>(W_Q, 1024, 4096, WbT, 1.f);
    transpose_convert_kernel<<<dim3(16, 16), 256, 0, stream>>>(W_K, 1024, 1024, WbT + 4096 * 1024, 1.f);
    transpose_convert_kernel<<<dim3(16, 16), 256, 0, stream>>>(W_V, 1024, 1024, WbT + 5120 * 1024, 1.f);
    transpose_convert_kernel<<<dim3(16, 64), 256, 0, stream>>>(W_O, 4096, 1024, WoT, 0.25f);
    bias_setup_kernel<<<28, 256, 0, stream>>>(b_Q, b_K, b_V, W_O_bias, biasQKV, bias_mean);

    gemm_bt_kernel<<<dim3(48, 8), 256, 0, stream>>>(Xb, WbT, biasQKV, QKVb, 1024, 6144, 1024);
    rope_qk_kernel<<<dim3(1024, 20), 128, 0, stream>>>(QKVb, ksr);
    v_transpose_kernel<<<dim3(16, 16), 256, 0, stream>>>(QKVb, Vtb);
    attn_kernel<<<dim3(64, 16), 256, 0, stream>>>(QKVb, Vtb, ksr, sinks, v_nulls, Ob);

    init_out_kernel<<<1024, 256, 0, stream>>>(bias_mean, out);
    gemm_bt64_splitk_kernel<<<dim3(16, 16, 4), 256, 0, stream>>>(Ob, WoT, out, 1024, 1024, 4096, 1024);
}

// Round 5
// 207.921 us; speedup vs baseline: 1.9862x; 1.0457x over previous
//
#include <hip/hip_runtime.h>
#include <math.h>

// ---------- types ----------
typedef __attribute__((ext_vector_type(4))) float  f32x4;
typedef __attribute__((ext_vector_type(8))) short  bf16x8;   // 8 bf16 in 4 VGPRs
typedef __attribute__((ext_vector_type(4))) short  s16x4;

#define SQUISH_SCALE 1.8137993642342178f   // pi/sqrt(3)

__device__ __forceinline__ float b2f(short u) {
    union { float f; unsigned b; } v; v.b = ((unsigned)(unsigned short)u) << 16; return v.f;
}
__device__ __forceinline__ short f2b(float f) {
    union { float f; unsigned b; } v; v.f = f;
    unsigned r = (v.b + 0x7FFFu + ((v.b >> 16) & 1u)) >> 16;   // RNE
    return (short)r;
}
__device__ __forceinline__ unsigned cvt_pk_bf16(float lo, float hi) {
    unsigned r;
    asm("v_cvt_pk_bf16_f32 %0, %1, %2" : "=v"(r) : "v"(lo), "v"(hi));
    return r;
}
// async global->LDS; lds base wave-uniform, HW adds lane*size
__device__ __forceinline__ void gll16(const void* g, void* l) {
    __builtin_amdgcn_global_load_lds((const __attribute__((address_space(1))) void*)g,
                                     (__attribute__((address_space(3))) void*)l, 16, 0, 0);
}
__device__ __forceinline__ void gll4(const void* g, void* l) {
    __builtin_amdgcn_global_load_lds((const __attribute__((address_space(1))) void*)g,
                                     (__attribute__((address_space(3))) void*)l, 4, 0, 0);
}

// ---------- unified prep kernel ----------
// roles by blockIdx.x:
//  [0,256)      convert X fp32->bf16
//  [256,1280)   transpose W_Q  (1024x4096 -> 4096x1024 bf16)
//  [1280,1536)  transpose W_K
//  [1536,1792)  transpose W_V
//  [1792,2816)  transpose W_O  (4096x1024 -> 1024x4096 bf16, x0.25)
//  [2816,2840)  biasQKV setup
//  [2840,3864)  init out = branch-mean of W_O_bias (computed directly from bO — no
//               intra-launch dependency; block order is undefined)
__device__ __forceinline__ void do_transpose(const float* __restrict__ src, int R, int C,
                                             short* __restrict__ dst, float scale,
                                             int c0, int r0, float (*tile)[65], int tid) {
    #pragma unroll
    for (int it = 0; it < 4; ++it) {
        int lin = it * 256 + tid;
        int r = lin >> 4, c4 = lin & 15;
        f32x4 v = *(const f32x4*)(src + (size_t)(r0 + r) * C + c0 + c4 * 4);
        #pragma unroll
        for (int k = 0; k < 4; ++k) tile[r][c4 * 4 + k] = v[k];
    }
    __syncthreads();
    #pragma unroll
    for (int it = 0; it < 4; ++it) {
        int lin = it * 256 + tid;
        int c = lin >> 4, rq = lin & 15;
        s16x4 o;
        #pragma unroll
        for (int k = 0; k < 4; ++k) o[k] = f2b(tile[rq * 4 + k][c] * scale);
        *(s16x4*)(dst + (size_t)(c0 + c) * R + r0 + rq * 4) = o;
    }
}

__global__ __launch_bounds__(256) void prep_kernel(
    const float* __restrict__ X, const float* __restrict__ W_Q, const float* __restrict__ W_K,
    const float* __restrict__ W_V, const float* __restrict__ W_O,
    const float* __restrict__ bQ, const float* __restrict__ bK, const float* __restrict__ bV,
    const float* __restrict__ bO,
    short* __restrict__ Xb, short* __restrict__ WbT, short* __restrict__ WoT,
    float* __restrict__ biasQKV, float* __restrict__ out) {
    __shared__ float tile[64][65];
    const int bid = blockIdx.x, tid = threadIdx.x;
    if (bid < 256) {
        int i = (bid * 256 + tid) * 16;
        #pragma unroll
        for (int k = 0; k < 4; ++k) {
            f32x4 v = *(const f32x4*)(X + i + k * 4);
            s16x4 o;
            o.x = f2b(v.x); o.y = f2b(v.y); o.z = f2b(v.z); o.w = f2b(v.w);
            *(s16x4*)(Xb + i + k * 4) = o;
        }
    } else if (bid < 1280) {
        int b2 = bid - 256;
        do_transpose(W_Q, 1024, 4096, WbT, 1.f, (b2 & 63) * 64, (b2 >> 6) * 64, tile, tid);
    } else if (bid < 1536) {
        int b2 = bid - 1280;
        do_transpose(W_K, 1024, 1024, WbT + 4096 * 1024, 1.f, (b2 & 15) * 64, (b2 >> 4) * 64, tile, tid);
    } else if (bid < 1792) {
        int b2 = bid - 1536;
        do_transpose(W_V, 1024, 1024, WbT + 5120 * 1024, 1.f, (b2 & 15) * 64, (b2 >> 4) * 64, tile, tid);
    } else if (bid < 2816) {
        int b2 = bid - 1792;
        do_transpose(W_O, 4096, 1024, WoT, 0.25f, (b2 & 15) * 64, (b2 >> 4) * 64, tile, tid);
    } else if (bid < 2840) {
        int i = (bid - 2816) * 256 + tid;
        if (i < 4096)      biasQKV[i] = bQ[i];
        else if (i < 5120) biasQKV[i] = bK[i - 4096];
        else               biasQKV[i] = bV[i - 5120];
    } else {
        int i = ((bid - 2840) * 256 + tid) * 4;
        f32x4 v;
        #pragma unroll
        for (int k = 0; k < 4; ++k) {
            int c = (i + k) & 1023;
            v[k] = 0.25f * (bO[c] + bO[1024 + c] + bO[2048 + c] + bO[3072 + c]);
        }
        *(f32x4*)(out + i) = v;
    }
}

// ---------- bf16 GEMM 128x128, double-buffered counted-vmcnt staging ----------
__global__ __launch_bounds__(256) void gemm_bt_kernel(
    const short* __restrict__ A, const short* __restrict__ BT,
    const float* __restrict__ bias, short* __restrict__ outB,
    int M, int N, int K) {
    __shared__ short lA[2][128][64];
    __shared__ short lB[2][128][64];
    const int tid = threadIdx.x;
    const int lane = tid & 63, wave = tid >> 6;
    const int l15 = lane & 15, l4 = lane >> 4;
    const int wr = wave >> 1, wc = wave & 1;
    const int n0 = blockIdx.x * 128, m0 = blockIdx.y * 128;

    f32x4 acc[4][4];
    const f32x4 fz = {0.f, 0.f, 0.f, 0.f};
    #pragma unroll
    for (int m = 0; m < 4; ++m)
        #pragma unroll
        for (int n = 0; n < 4; ++n) acc[m][n] = fz;

#define GSTAGE(k0_, b_) do {                                                   \
    _Pragma("unroll")                                                          \
    for (int it = 0; it < 4; ++it) {                                           \
        int lin0 = it * 256 + wave * 64;                                       \
        int lin = lin0 + lane;                                                 \
        int r = lin >> 3, c = (lin & 7) ^ (r & 7);                             \
        gll16(A  + (size_t)(m0 + r) * K + (k0_) + c * 8, (char*)lA[b_] + lin0 * 16); \
        gll16(BT + (size_t)(n0 + r) * K + (k0_) + c * 8, (char*)lB[b_] + lin0 * 16); \
    } } while (0)

    GSTAGE(0, 0);
    int cur = 0;
    for (int k0 = 0; k0 < K; k0 += 64) {
        if (k0 + 64 < K) {
            GSTAGE(k0 + 64, cur ^ 1);
            asm volatile("s_waitcnt vmcnt(8) lgkmcnt(0)" ::: "memory");
        } else {
            asm volatile("s_waitcnt vmcnt(0) lgkmcnt(0)" ::: "memory");
        }
        __builtin_amdgcn_s_barrier();
        #pragma unroll
        for (int kk = 0; kk < 2; ++kk) {
            bf16x8 af[4], bf_[4];
            #pragma unroll
            for (int m = 0; m < 4; ++m) {
                int row = wr * 64 + m * 16 + l15;
                int ch = (kk * 4 + l4) ^ (row & 7);
                af[m] = *(const bf16x8*)&lA[cur][row][ch << 3];
            }
            #pragma unroll
            for (int n = 0; n < 4; ++n) {
                int row = wc * 64 + n * 16 + l15;
                int ch = (kk * 4 + l4) ^ (row & 7);
                bf_[n] = *(const bf16x8*)&lB[cur][row][ch << 3];
            }
            #pragma unroll
            for (int m = 0; m < 4; ++m)
                #pragma unroll
                for (int n = 0; n < 4; ++n)
                    acc[m][n] = __builtin_amdgcn_mfma_f32_16x16x32_bf16(af[m], bf_[n], acc[m][n], 0, 0, 0);
        }
        asm volatile("" ::: "memory");
        __builtin_amdgcn_s_barrier();
        cur ^= 1;
    }
#undef GSTAGE
    #pragma unroll
    for (int m = 0; m < 4; ++m)
        #pragma unroll
        for (int n = 0; n < 4; ++n)
            #pragma unroll
            for (int r = 0; r < 4; ++r) {
                int row = m0 + wr * 64 + m * 16 + l4 * 4 + r;
                int col = n0 + wc * 64 + n * 16 + l15;
                outB[(size_t)row * N + col] = f2b(acc[m][n][r] + bias[col]);
            }
}

// ---------- out-proj: 128x128 tile, split-K=8, fp32 atomic accumulate ----------
__global__ __launch_bounds__(256) void gemm_bt_splitk_kernel(
    const short* __restrict__ A, const short* __restrict__ BT,
    float* __restrict__ out, int M, int N, int K, int KSLICE) {
    __shared__ short lA[2][128][64];
    __shared__ short lB[2][128][64];
    const int tid = threadIdx.x;
    const int lane = tid & 63, wave = tid >> 6;
    const int l15 = lane & 15, l4 = lane >> 4;
    const int wr = wave >> 1, wc = wave & 1;
    const int n0 = blockIdx.x * 128, m0 = blockIdx.y * 128;
    const int kbeg = blockIdx.z * KSLICE, kend = kbeg + KSLICE;

    f32x4 acc[4][4];
    const f32x4 fz = {0.f, 0.f, 0.f, 0.f};
    #pragma unroll
    for (int m = 0; m < 4; ++m)
        #pragma unroll
        for (int n = 0; n < 4; ++n) acc[m][n] = fz;

#define GSTAGE(k0_, b_) do {                                                   \
    _Pragma("unroll")                                                          \
    for (int it = 0; it < 4; ++it) {                                           \
        int lin0 = it * 256 + wave * 64;                                       \
        int lin = lin0 + lane;                                                 \
        int r = lin >> 3, c = (lin & 7) ^ (r & 7);                             \
        gll16(A  + (size_t)(m0 + r) * K + (k0_) + c * 8, (char*)lA[b_] + lin0 * 16); \
        gll16(BT + (size_t)(n0 + r) * K + (k0_) + c * 8, (char*)lB[b_] + lin0 * 16); \
    } } while (0)

    GSTAGE(kbeg, 0);
    int cur = 0;
    for (int k0 = kbeg; k0 < kend; k0 += 64) {
        if (k0 + 64 < kend) {
            GSTAGE(k0 + 64, cur ^ 1);
            asm volatile("s_waitcnt vmcnt(8) lgkmcnt(0)" ::: "memory");
        } else {
            asm volatile("s_waitcnt vmcnt(0) lgkmcnt(0)" ::: "memory");
        }
        __builtin_amdgcn_s_barrier();
        #pragma unroll
        for (int kk = 0; kk < 2; ++kk) {
            bf16x8 af[4], bf_[4];
            #pragma unroll
            for (int m = 0; m < 4; ++m) {
                int row = wr * 64 + m * 16 + l15;
                int ch = (kk * 4 + l4) ^ (row & 7);
                af[m] = *(const bf16x8*)&lA[cur][row][ch << 3];
            }
            #pragma unroll
            for (int n = 0; n < 4; ++n) {
                int row = wc * 64 + n * 16 + l15;
                int ch = (kk * 4 + l4) ^ (row & 7);
                bf_[n] = *(const bf16x8*)&lB[cur][row][ch << 3];
            }
            #pragma unroll
            for (int m = 0; m < 4; ++m)
                #pragma unroll
                for (int n = 0; n < 4; ++n)
                    acc[m][n] = __builtin_amdgcn_mfma_f32_16x16x32_bf16(af[m], bf_[n], acc[m][n], 0, 0, 0);
        }
        asm volatile("" ::: "memory");
        __builtin_amdgcn_s_barrier();
        cur ^= 1;
    }
#undef GSTAGE
    #pragma unroll
    for (int m = 0; m < 4; ++m)
        #pragma unroll
        for (int n = 0; n < 4; ++n)
            #pragma unroll
            for (int r = 0; r < 4; ++r) {
                int row = m0 + wr * 64 + m * 16 + l4 * 4 + r;
                int col = n0 + wc * 64 + n * 16 + l15;
                unsafeAtomicAdd(&out[(size_t)row * N + col], acc[m][n][r]);
            }
}

// ---------- fused RoPE + ksr + V-transpose ----------
// blocks [0,1280): rope grid-stride over 1024 t x 80 heads x 32 j (8 items/thread)
// blocks [1280,1536): V transpose (T x 16 x 64) -> Vt (16 x 64 x T)
__global__ __launch_bounds__(256) void rope_vt_kernel(short* __restrict__ QKVb,
                                                      float* __restrict__ ksr,
                                                      short* __restrict__ Vtb) {
    __shared__ short tile[64][72];
    const int bid = blockIdx.x, tid = threadIdx.x;
    if (bid < 1280) {
        int base = bid * 256 + tid;
        #pragma unroll
        for (int it = 0; it < 8; ++it) {
            int item = base + it * 327680;
            int j = item & 31;
            int rem = item >> 5;
            int head = rem % 80;
            int t = rem / 80;
            short* p;
            if (head < 64) p = QKVb + (size_t)t * 6144 + head * 64;
            else           p = QKVb + (size_t)t * 6144 + 4096 + (head - 64) * 64;
            float x1 = b2f(p[2 * j]), x2 = b2f(p[2 * j + 1]);
            float freq = (float)t * __builtin_exp2f(-(float)j * 0.41524101186092033f); // 10000^(-j/32)
            float sn = __sinf(freq), cs = __cosf(freq);
            float o1 = x1 * cs - x2 * sn;
            float o2 = x1 * sn + x2 * cs;
            p[j]      = f2b(o1);
            p[32 + j] = f2b(o2);
            if (head >= 64) {
                float ss = o1 * o1 + o2 * o2;
                #pragma unroll
                for (int off = 16; off; off >>= 1) ss += __shfl_xor(ss, off, 32);
                if (j == 0) ksr[(head - 64) * 1024 + t] = 0.125f * rsqrtf(fmaxf(ss, 1e-6f));
            }
        }
    } else {
        int b2 = bid - 1280;
        int h = b2 >> 4, t0 = (b2 & 15) * 64;
        #pragma unroll
        for (int it = 0; it < 16; ++it) {
            int lin = it * 256 + tid;
            int r = lin >> 6, d = lin & 63;
            tile[r][d] = QKVb[(size_t)(t0 + r) * 6144 + 5120 + h * 64 + d];
        }
        __syncthreads();
        #pragma unroll
        for (int it = 0; it < 16; ++it) {
            int lin = it * 256 + tid;
            int d = lin >> 6, c = lin & 63;
            Vtb[(size_t)(h * 64 + d) * 1024 + t0 + c] = tile[c][d];
        }
    }
}

// ---------- attention (double-buffered K/V staging, counted vmcnt) ----------
// grid (64 heads, 16 q-tiles of 64 rows; heaviest first), block 256 (4 waves x 16 q-rows).
__global__ __launch_bounds__(256, 3) void attn_kernel(
    const short* __restrict__ QKVb, const short* __restrict__ Vtb,
    const float* __restrict__ ksr, const float* __restrict__ sinks,
    const float* __restrict__ vnulls, short* __restrict__ Ob) {
    __shared__ short lK[2][64][64];
    __shared__ short lV[2][64][64];
    __shared__ float lks[2][64];
    __shared__ float lvn[64];
    __shared__ short lP[4][16][64];

    const int tid = threadIdx.x;
    const int lane = tid & 63, wave = tid >> 6;
    const int l15 = lane & 15, l4 = lane >> 4;
    const int h = blockIdx.x;
    const int qt = 15 - blockIdx.y;          // heavy tiles dispatch first
    const int h16 = h & 15;
    const int t0 = qt * 64;
    const float sink = sinks[h];
    if (tid < 64) lvn[tid] = vnulls[h * 64 + tid];

    // Q fragments (B-operand: lane holds q = l15, d-slice = kk*32 + l4*8)
    const int q_abs = t0 + wave * 16 + l15;
    bf16x8 aq[2];
    #pragma unroll
    for (int kk = 0; kk < 2; ++kk)
        aq[kk] = *(const bf16x8*)(QKVb + (size_t)q_abs * 6144 + h * 64 + kk * 32 + l4 * 8);

    const f32x4 fz = {0.f, 0.f, 0.f, 0.f};
    f32x4 acc_o[4];
    #pragma unroll
    for (int n = 0; n < 4; ++n) acc_o[n] = fz;
    float tot = 0.f;

#define ASTAGE(s0_, b_) do {                                                          \
    int lin0 = wave * 64;                                                             \
    int lin = lin0 + lane;                                                            \
    int r = lin >> 3, c = (lin & 7) ^ (r & 7);                                        \
    gll16(QKVb + (size_t)((s0_) + r) * 6144 + 4096 + h16 * 64 + c * 8, (char*)lK[b_] + lin0 * 16); \
    gll16(Vtb + (size_t)(h16 * 64 + r) * 1024 + (s0_) + c * 8,         (char*)lV[b_] + lin0 * 16); \
    lin0 += 256; lin = lin0 + lane; r = lin >> 3; c = (lin & 7) ^ (r & 7);            \
    gll16(QKVb + (size_t)((s0_) + r) * 6144 + 4096 + h16 * 64 + c * 8, (char*)lK[b_] + lin0 * 16); \
    gll16(Vtb + (size_t)(h16 * 64 + r) * 1024 + (s0_) + c * 8,         (char*)lV[b_] + lin0 * 16); \
    gll4(ksr + h16 * 1024 + (s0_) + lane, (char*)lks[b_]);                            \
} while (0)

    const int nkt = qt + 1;
    ASTAGE(0, 0);
    int cur = 0;
    for (int kt = 0; kt < nkt; ++kt) {
        int s0 = kt * 64;
        if (kt + 1 < nkt) {
            ASTAGE(s0 + 64, cur ^ 1);
            asm volatile("s_waitcnt vmcnt(5) lgkmcnt(0)" ::: "memory");
        } else {
            asm volatile("s_waitcnt vmcnt(0) lgkmcnt(0)" ::: "memory");
        }
        __builtin_amdgcn_s_barrier();

        // QK^T swapped: A = K (rows = keys), B = Q (cols = q)
        f32x4 accs[4];
        #pragma unroll
        for (int n = 0; n < 4; ++n) accs[n] = fz;
        #pragma unroll
        for (int kk = 0; kk < 2; ++kk) {
            bf16x8 bk[4];
            #pragma unroll
            for (int n = 0; n < 4; ++n) {
                int row = n * 16 + l15;
                int ch = (kk * 4 + l4) ^ (row & 7);
                bk[n] = *(const bf16x8*)&lK[cur][row][ch << 3];
            }
            #pragma unroll
            for (int n = 0; n < 4; ++n)
                accs[n] = __builtin_amdgcn_mfma_f32_16x16x32_bf16(bk[n], aq[kk], accs[n], 0, 0, 0);
        }

        // weights: softplus -> causal -> SiLU gate -> sink threshold; pack to lP
        #pragma unroll
        for (int n = 0; n < 4; ++n) {
            f32x4 ksv = *(const f32x4*)&lks[cur][n * 16 + l4 * 4];
            float w4[4];
            #pragma unroll
            for (int r = 0; r < 4; ++r) {
                int k_abs = s0 + n * 16 + l4 * 4 + r;
                float z = accs[n][r] * ksv[r];
                float e = __expf(-fabsf(z));
                float w = fmaxf(z, 0.f) + __logf(1.f + e);
                w = (k_abs <= q_abs) ? w : 0.f;
                float g = __expf(-SQUISH_SCALE * w);
                w = w * __builtin_amdgcn_rcpf(1.f + g);
                w = (w >= sink) ? w : 0.f;
                tot += w;
                w4[r] = w;
            }
            unsigned pa = cvt_pk_bf16(w4[0], w4[1]);
            unsigned pb = cvt_pk_bf16(w4[2], w4[3]);
            int ch = (2 * n + (l4 >> 1)) ^ (l15 & 7);
            uint2 val; val.x = pa; val.y = pb;
            *(uint2*)&lP[wave][l15][ch * 8 + (l4 & 1) * 4] = val;
        }

        // PV: A = P (rows = q), B = V^T (cols = d); per-wave private lP
        #pragma unroll
        for (int kk = 0; kk < 2; ++kk) {
            bf16x8 ap = *(const bf16x8*)&lP[wave][l15][((kk * 4 + l4) ^ (l15 & 7)) << 3];
            bf16x8 bv[4];
            #pragma unroll
            for (int n = 0; n < 4; ++n) {
                int row = n * 16 + l15;
                int ch = (kk * 4 + l4) ^ (row & 7);
                bv[n] = *(const bf16x8*)&lV[cur][row][ch << 3];
            }
            #pragma unroll
            for (int n = 0; n < 4; ++n)
                acc_o[n] = __builtin_amdgcn_mfma_f32_16x16x32_bf16(ap, bv[n], acc_o[n], 0, 0, 0);
        }
        asm volatile("" ::: "memory");
        __builtin_amdgcn_s_barrier();
        cur ^= 1;
    }
#undef ASTAGE

    // row totals: lane's tot covers its 16 k-rows; sum across the 4 l4-groups
    tot += __shfl_xor(tot, 16, 64);
    tot += __shfl_xor(tot, 32, 64);
    float tq[4];
    #pragma unroll
    for (int r = 0; r < 4; ++r) tq[r] = __shfl(tot, l4 * 4 + r, 64);

    // epilogue: out = (acc + sink*vnull) / total
    #pragma unroll
    for (int r = 0; r < 4; ++r) {
        float inv = __builtin_amdgcn_rcpf(tq[r] + sink + 1e-6f);
        int trow = t0 + wave * 16 + l4 * 4 + r;
        #pragma unroll
        for (int n = 0; n < 4; ++n) {
            int d = n * 16 + l15;
            float val = (acc_o[n][r] + sink * lvn[d]) * inv;
            Ob[(size_t)trow * 4096 + h * 64 + d] = f2b(val);
        }
    }
}

// ---------- launch ----------
extern "C" void kernel_launch(void* const* d_in, const int* in_sizes, int n_in,
                              void* d_out, int out_size, void* d_ws, size_t ws_size,
                              hipStream_t stream) {
    const float* X        = (const float*)d_in[0];
    const float* W_Q      = (const float*)d_in[1];
    const float* b_Q      = (const float*)d_in[2];
    const float* W_K      = (const float*)d_in[3];
    const float* b_K      = (const float*)d_in[4];
    const float* W_V      = (const float*)d_in[5];
    const float* b_V      = (const float*)d_in[6];
    const float* sinks    = (const float*)d_in[7];
    const float* v_nulls  = (const float*)d_in[8];
    const float* W_O      = (const float*)d_in[9];
    const float* W_O_bias = (const float*)d_in[10];
    float* out = (float*)d_out;
    char* ws = (char*)d_ws;

    short* Xb        = (short*)(ws + 0);          //  2 MB  (1024x1024)
    short* WbT       = (short*)(ws + 2097152);    // 12 MB  (6144x1024)
    short* WoT       = (short*)(ws + 14680064);   //  8 MB  (1024x4096), pre-scaled 0.25
    short* QKVb      = (short*)(ws + 23068672);   // 12 MB  (1024x6144)
    short* Vtb       = (short*)(ws + 35651584);   //  2 MB  (16x64x1024)
    short* Ob        = (short*)(ws + 37748736);   //  8 MB  (1024x4096)
    float* ksr       = (float*)(ws + 46137344);   // 64 KB  (16x1024)
    float* biasQKV   = (float*)(ws + 46202880);   // 24 KB

    prep_kernel<<<3864, 256, 0, stream>>>(X, W_Q, W_K, W_V, W_O, b_Q, b_K, b_V, W_O_bias,
                                          Xb, WbT, WoT, biasQKV, out);
    gemm_bt_kernel<<<dim3(48, 8), 256, 0, stream>>>(Xb, WbT, biasQKV, QKVb, 1024, 6144, 1024);
    rope_vt_kernel<<<1536, 256, 0, stream>>>(QKVb, ksr, Vtb);
    attn_kernel<<<dim3(64, 16), 256, 0, stream>>>(QKVb, Vtb, ksr, sinks, v_nulls, Ob);
    gemm_bt_splitk_kernel<<<dim3(8, 8, 8), 256, 0, stream>>>(Ob, WoT, out, 1024, 1024, 4096, 512);
}

// Round 6
// 204.738 us; speedup vs baseline: 2.0171x; 1.0155x over previous
//
#include <hip/hip_runtime.h>
#include <math.h>

// ---------- types ----------
typedef __attribute__((ext_vector_type(4))) float  f32x4;
typedef __attribute__((ext_vector_type(8))) short  bf16x8;   // 8 bf16 in 4 VGPRs
typedef __attribute__((ext_vector_type(4))) short  s16x4;

#define SQUISH_U 1.8137993642342178f      // pi/sqrt(3)  (applied to u = sp(z)/ln2)
#define LN2F     0.69314718055994531f

__device__ __forceinline__ float b2f(short u) {
    union { float f; unsigned b; } v; v.b = ((unsigned)(unsigned short)u) << 16; return v.f;
}
__device__ __forceinline__ short f2b(float f) {
    union { float f; unsigned b; } v; v.f = f;
    unsigned r = (v.b + 0x7FFFu + ((v.b >> 16) & 1u)) >> 16;   // RNE
    return (short)r;
}
__device__ __forceinline__ unsigned cvt_pk_bf16(float lo, float hi) {
    unsigned r;
    asm("v_cvt_pk_bf16_f32 %0, %1, %2" : "=v"(r) : "v"(lo), "v"(hi));
    return r;
}
// async global->LDS; lds base wave-uniform, HW adds lane*size
__device__ __forceinline__ void gll16(const void* g, void* l) {
    __builtin_amdgcn_global_load_lds((const __attribute__((address_space(1))) void*)g,
                                     (__attribute__((address_space(3))) void*)l, 16, 0, 0);
}
__device__ __forceinline__ void gll4(const void* g, void* l) {
    __builtin_amdgcn_global_load_lds((const __attribute__((address_space(1))) void*)g,
                                     (__attribute__((address_space(3))) void*)l, 4, 0, 0);
}

// ---------- unified prep kernel (identical to R4-pass version) ----------
__device__ __forceinline__ void do_transpose(const float* __restrict__ src, int R, int C,
                                             short* __restrict__ dst, float scale,
                                             int c0, int r0, float (*tile)[65], int tid) {
    #pragma unroll
    for (int it = 0; it < 4; ++it) {
        int lin = it * 256 + tid;
        int r = lin >> 4, c4 = lin & 15;
        f32x4 v = *(const f32x4*)(src + (size_t)(r0 + r) * C + c0 + c4 * 4);
        #pragma unroll
        for (int k = 0; k < 4; ++k) tile[r][c4 * 4 + k] = v[k];
    }
    __syncthreads();
    #pragma unroll
    for (int it = 0; it < 4; ++it) {
        int lin = it * 256 + tid;
        int c = lin >> 4, rq = lin & 15;
        s16x4 o;
        #pragma unroll
        for (int k = 0; k < 4; ++k) o[k] = f2b(tile[rq * 4 + k][c] * scale);
        *(s16x4*)(dst + (size_t)(c0 + c) * R + r0 + rq * 4) = o;
    }
}

__global__ __launch_bounds__(256) void prep_kernel(
    const float* __restrict__ X, const float* __restrict__ W_Q, const float* __restrict__ W_K,
    const float* __restrict__ W_V, const float* __restrict__ W_O,
    const float* __restrict__ bQ, const float* __restrict__ bK, const float* __restrict__ bV,
    const float* __restrict__ bO,
    short* __restrict__ Xb, short* __restrict__ WbT, short* __restrict__ WoT,
    float* __restrict__ biasQKV, float* __restrict__ out) {
    __shared__ float tile[64][65];
    const int bid = blockIdx.x, tid = threadIdx.x;
    if (bid < 256) {
        int i = (bid * 256 + tid) * 16;
        #pragma unroll
        for (int k = 0; k < 4; ++k) {
            f32x4 v = *(const f32x4*)(X + i + k * 4);
            s16x4 o;
            o.x = f2b(v.x); o.y = f2b(v.y); o.z = f2b(v.z); o.w = f2b(v.w);
            *(s16x4*)(Xb + i + k * 4) = o;
        }
    } else if (bid < 1280) {
        int b2 = bid - 256;
        do_transpose(W_Q, 1024, 4096, WbT, 1.f, (b2 & 63) * 64, (b2 >> 6) * 64, tile, tid);
    } else if (bid < 1536) {
        int b2 = bid - 1280;
        do_transpose(W_K, 1024, 1024, WbT + 4096 * 1024, 1.f, (b2 & 15) * 64, (b2 >> 4) * 64, tile, tid);
    } else if (bid < 1792) {
        int b2 = bid - 1536;
        do_transpose(W_V, 1024, 1024, WbT + 5120 * 1024, 1.f, (b2 & 15) * 64, (b2 >> 4) * 64, tile, tid);
    } else if (bid < 2816) {
        int b2 = bid - 1792;
        do_transpose(W_O, 4096, 1024, WoT, 0.25f, (b2 & 15) * 64, (b2 >> 4) * 64, tile, tid);
    } else if (bid < 2840) {
        int i = (bid - 2816) * 256 + tid;
        if (i < 4096)      biasQKV[i] = bQ[i];
        else if (i < 5120) biasQKV[i] = bK[i - 4096];
        else               biasQKV[i] = bV[i - 5120];
    } else {
        int i = ((bid - 2840) * 256 + tid) * 4;
        f32x4 v;
        #pragma unroll
        for (int k = 0; k < 4; ++k) {
            int c = (i + k) & 1023;
            v[k] = 0.25f * (bO[c] + bO[1024 + c] + bO[2048 + c] + bO[3072 + c]);
        }
        *(f32x4*)(out + i) = v;
    }
}

// ---------- bf16 GEMM, 64x128 tile, dbuf counted-vmcnt: QKV projection ----------
// grid (N/128, M/64); 4 waves 2m x 2n, each 32x64 (2x4 frags).
#define GSTAGE_64x128(k0_, b_) do {                                            \
    _Pragma("unroll")                                                          \
    for (int it = 0; it < 2; ++it) {                                           \
        int lin0 = it * 256 + wave * 64;                                       \
        int lin = lin0 + lane;                                                 \
        int r = lin >> 3, c = (lin & 7) ^ (r & 7);                             \
        gll16(A + (size_t)(m0 + r) * K + (k0_) + c * 8, (char*)lA[b_] + lin0 * 16); \
    }                                                                          \
    _Pragma("unroll")                                                          \
    for (int it = 0; it < 4; ++it) {                                           \
        int lin0 = it * 256 + wave * 64;                                       \
        int lin = lin0 + lane;                                                 \
        int r = lin >> 3, c = (lin & 7) ^ (r & 7);                             \
        gll16(BT + (size_t)(n0 + r) * K + (k0_) + c * 8, (char*)lB[b_] + lin0 * 16); \
    } } while (0)

#define GEMM_CORE_64x128(kbeg_, kend_)                                         \
    GSTAGE_64x128(kbeg_, 0);                                                   \
    int cur = 0;                                                               \
    for (int k0 = (kbeg_); k0 < (kend_); k0 += 64) {                           \
        if (k0 + 64 < (kend_)) {                                               \
            GSTAGE_64x128(k0 + 64, cur ^ 1);                                   \
            asm volatile("s_waitcnt vmcnt(6) lgkmcnt(0)" ::: "memory");        \
        } else {                                                               \
            asm volatile("s_waitcnt vmcnt(0) lgkmcnt(0)" ::: "memory");        \
        }                                                                      \
        __builtin_amdgcn_s_barrier();                                          \
        _Pragma("unroll")                                                      \
        for (int kk = 0; kk < 2; ++kk) {                                       \
            bf16x8 af[2], bf_[4];                                              \
            _Pragma("unroll")                                                  \
            for (int m = 0; m < 2; ++m) {                                      \
                int row = wr * 32 + m * 16 + l15;                              \
                int ch = (kk * 4 + l4) ^ (row & 7);                            \
                af[m] = *(const bf16x8*)&lA[cur][row][ch << 3];                \
            }                                                                  \
            _Pragma("unroll")                                                  \
            for (int n = 0; n < 4; ++n) {                                      \
                int row = wc * 64 + n * 16 + l15;                              \
                int ch = (kk * 4 + l4) ^ (row & 7);                            \
                bf_[n] = *(const bf16x8*)&lB[cur][row][ch << 3];               \
            }                                                                  \
            _Pragma("unroll")                                                  \
            for (int m = 0; m < 2; ++m)                                        \
                _Pragma("unroll")                                              \
                for (int n = 0; n < 4; ++n)                                    \
                    acc[m][n] = __builtin_amdgcn_mfma_f32_16x16x32_bf16(af[m], bf_[n], acc[m][n], 0, 0, 0); \
        }                                                                      \
        asm volatile("" ::: "memory");                                         \
        __builtin_amdgcn_s_barrier();                                          \
        cur ^= 1;                                                              \
    }

__global__ __launch_bounds__(256, 3) void gemm_qkv_kernel(
    const short* __restrict__ A, const short* __restrict__ BT,
    const float* __restrict__ bias, short* __restrict__ outB,
    int M, int N, int K) {
    __shared__ short lA[2][64][64];
    __shared__ short lB[2][128][64];
    const int tid = threadIdx.x;
    const int lane = tid & 63, wave = tid >> 6;
    const int l15 = lane & 15, l4 = lane >> 4;
    const int wr = wave >> 1, wc = wave & 1;
    const int n0 = blockIdx.x * 128, m0 = blockIdx.y * 64;

    f32x4 acc[2][4];
    const f32x4 fz = {0.f, 0.f, 0.f, 0.f};
    #pragma unroll
    for (int m = 0; m < 2; ++m)
        #pragma unroll
        for (int n = 0; n < 4; ++n) acc[m][n] = fz;

    GEMM_CORE_64x128(0, K);

    #pragma unroll
    for (int m = 0; m < 2; ++m)
        #pragma unroll
        for (int n = 0; n < 4; ++n)
            #pragma unroll
            for (int r = 0; r < 4; ++r) {
                int row = m0 + wr * 32 + m * 16 + l4 * 4 + r;
                int col = n0 + wc * 64 + n * 16 + l15;
                outB[(size_t)row * N + col] = f2b(acc[m][n][r] + bias[col]);
            }
}

// ---------- out-proj: 64x128 tile, split-K, fp32 atomic accumulate ----------
__global__ __launch_bounds__(256, 3) void gemm_op_kernel(
    const short* __restrict__ A, const short* __restrict__ BT,
    float* __restrict__ out, int M, int N, int K, int KSLICE) {
    __shared__ short lA[2][64][64];
    __shared__ short lB[2][128][64];
    const int tid = threadIdx.x;
    const int lane = tid & 63, wave = tid >> 6;
    const int l15 = lane & 15, l4 = lane >> 4;
    const int wr = wave >> 1, wc = wave & 1;
    const int n0 = blockIdx.x * 128, m0 = blockIdx.y * 64;
    const int kbeg = blockIdx.z * KSLICE, kend = kbeg + KSLICE;

    f32x4 acc[2][4];
    const f32x4 fz = {0.f, 0.f, 0.f, 0.f};
    #pragma unroll
    for (int m = 0; m < 2; ++m)
        #pragma unroll
        for (int n = 0; n < 4; ++n) acc[m][n] = fz;

    GEMM_CORE_64x128(kbeg, kend);

    #pragma unroll
    for (int m = 0; m < 2; ++m)
        #pragma unroll
        for (int n = 0; n < 4; ++n)
            #pragma unroll
            for (int r = 0; r < 4; ++r) {
                int row = m0 + wr * 32 + m * 16 + l4 * 4 + r;
                int col = n0 + wc * 64 + n * 16 + l15;
                unsafeAtomicAdd(&out[(size_t)row * N + col], acc[m][n][r]);
            }
}

// ---------- fused RoPE + ksr + V-transpose ----------
// ksr stores log2e * 0.125 * rsqrt(|k|^2) so attn's exp2 needs no extra scale.
__global__ __launch_bounds__(256) void rope_vt_kernel(short* __restrict__ QKVb,
                                                      float* __restrict__ ksr,
                                                      short* __restrict__ Vtb) {
    __shared__ short tile[64][72];
    const int bid = blockIdx.x, tid = threadIdx.x;
    if (bid < 1280) {
        int base = bid * 256 + tid;
        #pragma unroll
        for (int it = 0; it < 8; ++it) {
            int item = base + it * 327680;
            int j = item & 31;
            int rem = item >> 5;
            int head = rem % 80;
            int t = rem / 80;
            short* p;
            if (head < 64) p = QKVb + (size_t)t * 6144 + head * 64;
            else           p = QKVb + (size_t)t * 6144 + 4096 + (head - 64) * 64;
            float x1 = b2f(p[2 * j]), x2 = b2f(p[2 * j + 1]);
            float freq = (float)t * __builtin_exp2f(-(float)j * 0.41524101186092033f); // 10000^(-j/32)
            float sn = __sinf(freq), cs = __cosf(freq);
            float o1 = x1 * cs - x2 * sn;
            float o2 = x1 * sn + x2 * cs;
            p[j]      = f2b(o1);
            p[32 + j] = f2b(o2);
            if (head >= 64) {
                float ss = o1 * o1 + o2 * o2;
                #pragma unroll
                for (int off = 16; off; off >>= 1) ss += __shfl_xor(ss, off, 32);
                if (j == 0) ksr[(head - 64) * 1024 + t] = 0.18033688011112042f * rsqrtf(fmaxf(ss, 1e-6f));
            }
        }
    } else {
        int b2 = bid - 1280;
        int h = b2 >> 4, t0 = (b2 & 15) * 64;
        #pragma unroll
        for (int it = 0; it < 16; ++it) {
            int lin = it * 256 + tid;
            int r = lin >> 6, d = lin & 63;
            tile[r][d] = QKVb[(size_t)(t0 + r) * 6144 + 5120 + h * 64 + d];
        }
        __syncthreads();
        #pragma unroll
        for (int it = 0; it < 16; ++it) {
            int lin = it * 256 + tid;
            int d = lin >> 6, c = lin & 63;
            Vtb[(size_t)(h * 64 + d) * 1024 + t0 + c] = tile[c][d];
        }
    }
}

// ---------- attention, k-split for load balance + occupancy ----------
// grid (64 heads, 24 slots). Slots (qt, kbeg, kend), descending work; qt>=8 split in two.
// Split blocks atomically add partial O / sum-w into Of/totf; norm_kernel finalizes.
__constant__ __device__ const signed char TQT[24] = {15,15,14, 7,14,13,13,12, 6,12,11,11,10, 5,10, 9, 9, 8, 4, 8, 3, 2, 1, 0};
__constant__ __device__ const signed char TKB[24] = { 0, 8, 0, 0, 8, 0, 7, 0, 0, 7, 0, 6, 0, 0, 6, 0, 5, 0, 0, 5, 0, 0, 0, 0};
__constant__ __device__ const signed char TKE[24] = { 8,16, 8, 8,15, 7,14, 7, 7,13, 6,12, 6, 6,11, 5,10, 5, 5, 9, 4, 3, 2, 1};

__global__ __launch_bounds__(256, 6) void attn_kernel(
    const short* __restrict__ QKVb, const short* __restrict__ Vtb,
    const float* __restrict__ ksr, const float* __restrict__ sinks,
    const float* __restrict__ vnulls, short* __restrict__ Ob,
    float* __restrict__ Of, float* __restrict__ totf) {
    __shared__ short lK[64][64];
    __shared__ short lV[64][64];
    __shared__ float lks[64];
    __shared__ float lvn[64];
    __shared__ short lP[4][16][64];

    const int tid = threadIdx.x;
    const int lane = tid & 63, wave = tid >> 6;
    const int l15 = lane & 15, l4 = lane >> 4;
    const int h = blockIdx.x;
    const int slot = blockIdx.y;
    const int qt = TQT[slot], kb = TKB[slot], ke = TKE[slot];
    const bool single = (kb == 0) && (ke == qt + 1);
    const int h16 = h & 15;
    const int t0 = qt * 64;
    const float sink = sinks[h];
    if (tid < 64) lvn[tid] = vnulls[h * 64 + tid];

    // Q fragments (B-operand: lane holds q = l15, d-slice = kk*32 + l4*8)
    const int q_abs = t0 + wave * 16 + l15;
    bf16x8 aq[2];
    #pragma unroll
    for (int kk = 0; kk < 2; ++kk)
        aq[kk] = *(const bf16x8*)(QKVb + (size_t)q_abs * 6144 + h * 64 + kk * 32 + l4 * 8);

    const f32x4 fz = {0.f, 0.f, 0.f, 0.f};
    f32x4 acc_o[4];
    #pragma unroll
    for (int n = 0; n < 4; ++n) acc_o[n] = fz;
    float tot = 0.f;

#define ASTAGE(s0_) do {                                                              \
    int lin0 = wave * 64;                                                             \
    int lin = lin0 + lane;                                                            \
    int r = lin >> 3, c = (lin & 7) ^ (r & 7);                                        \
    gll16(QKVb + (size_t)((s0_) + r) * 6144 + 4096 + h16 * 64 + c * 8, (char*)lK + lin0 * 16); \
    gll16(Vtb + (size_t)(h16 * 64 + r) * 1024 + (s0_) + c * 8,         (char*)lV + lin0 * 16); \
    lin0 += 256; lin = lin0 + lane; r = lin >> 3; c = (lin & 7) ^ (r & 7);            \
    gll16(QKVb + (size_t)((s0_) + r) * 6144 + 4096 + h16 * 64 + c * 8, (char*)lK + lin0 * 16); \
    gll16(Vtb + (size_t)(h16 * 64 + r) * 1024 + (s0_) + c * 8,         (char*)lV + lin0 * 16); \
    gll4(ksr + h16 * 1024 + (s0_) + lane, (char*)lks);                                \
} while (0)

    for (int kt = kb; kt < ke; ++kt) {
        int s0 = kt * 64;
        __syncthreads();                         // previous tile's LDS reads complete
        ASTAGE(s0);
        asm volatile("s_waitcnt vmcnt(0)" ::: "memory");
        __syncthreads();

        // QK^T swapped: A = K (rows = keys), B = Q (cols = q)
        f32x4 accs[4];
        #pragma unroll
        for (int n = 0; n < 4; ++n) accs[n] = fz;
        #pragma unroll
        for (int kk = 0; kk < 2; ++kk) {
            bf16x8 bk[4];
            #pragma unroll
            for (int n = 0; n < 4; ++n) {
                int row = n * 16 + l15;
                int ch = (kk * 4 + l4) ^ (row & 7);
                bk[n] = *(const bf16x8*)&lK[row][ch << 3];
            }
            #pragma unroll
            for (int n = 0; n < 4; ++n)
                accs[n] = __builtin_amdgcn_mfma_f32_16x16x32_bf16(bk[n], aq[kk], accs[n], 0, 0, 0);
        }

        // weights via exp2/log2:  u = log2(1+2^(z*log2e));  w = ln2*u*sigmoid-gate
        #pragma unroll
        for (int n = 0; n < 4; ++n) {
            f32x4 ksv = *(const f32x4*)&lks[n * 16 + l4 * 4];
            float w4[4];
            #pragma unroll
            for (int r = 0; r < 4; ++r) {
                int k_abs = s0 + n * 16 + l4 * 4 + r;
                float zz = accs[n][r] * ksv[r];                       // z*log2e (ksr pre-scaled)
                float t = __builtin_amdgcn_exp2f(zz);
                float u = __builtin_amdgcn_logf(1.f + t);             // log2(1+e^z)
                u = (k_abs <= q_abs) ? u : 0.f;
                float g = __builtin_amdgcn_rcpf(1.f + __builtin_amdgcn_exp2f(-SQUISH_U * u));
                float w = LN2F * u * g;
                w = (w >= sink) ? w : 0.f;
                tot += w;
                w4[r] = w;
            }
            unsigned pa = cvt_pk_bf16(w4[0], w4[1]);
            unsigned pb = cvt_pk_bf16(w4[2], w4[3]);
            int ch = (2 * n + (l4 >> 1)) ^ (l15 & 7);
            uint2 val; val.x = pa; val.y = pb;
            *(uint2*)&lP[wave][l15][ch * 8 + (l4 & 1) * 4] = val;
        }

        // PV: A = P (rows = q), B = V^T (cols = d); per-wave private lP
        #pragma unroll
        for (int kk = 0; kk < 2; ++kk) {
            bf16x8 ap = *(const bf16x8*)&lP[wave][l15][((kk * 4 + l4) ^ (l15 & 7)) << 3];
            bf16x8 bv[4];
            #pragma unroll
            for (int n = 0; n < 4; ++n) {
                int row = n * 16 + l15;
                int ch = (kk * 4 + l4) ^ (row & 7);
                bv[n] = *(const bf16x8*)&lV[row][ch << 3];
            }
            #pragma unroll
            for (int n = 0; n < 4; ++n)
                acc_o[n] = __builtin_amdgcn_mfma_f32_16x16x32_bf16(ap, bv[n], acc_o[n], 0, 0, 0);
        }
    }
#undef ASTAGE

    // row totals: sum each q-row's 4 l4-slices
    tot += __shfl_xor(tot, 16, 64);
    tot += __shfl_xor(tot, 32, 64);

    if (single) {
        float tq[4];
        #pragma unroll
        for (int r = 0; r < 4; ++r) tq[r] = __shfl(tot, l4 * 4 + r, 64);
        #pragma unroll
        for (int r = 0; r < 4; ++r) {
            float inv = __builtin_amdgcn_rcpf(tq[r] + sink + 1e-6f);
            int trow = t0 + wave * 16 + l4 * 4 + r;
            #pragma unroll
            for (int n = 0; n < 4; ++n) {
                int d = n * 16 + l15;
                float val = (acc_o[n][r] + sink * lvn[d]) * inv;
                Ob[(size_t)trow * 4096 + h * 64 + d] = f2b(val);
            }
        }
    } else {
        // partial: atomically accumulate into Of (rows 512..1023 per head) and totf
        if (lane < 16)
            unsafeAtomicAdd(&totf[h * 512 + (t0 - 512) + wave * 16 + l15], tot);
        #pragma unroll
        for (int r = 0; r < 4; ++r) {
            int pr = h * 512 + (t0 - 512) + wave * 16 + l4 * 4 + r;
            #pragma unroll
            for (int n = 0; n < 4; ++n)
                unsafeAtomicAdd(&Of[(size_t)pr * 64 + n * 16 + l15], acc_o[n][r]);
        }
    }
}

// ---------- finalize split rows: Ob = (Of + sink*vnull) / (tot + sink + eps) ----------
__global__ __launch_bounds__(256) void norm_kernel(
    const float* __restrict__ Of, const float* __restrict__ totf,
    const float* __restrict__ sinks, const float* __restrict__ vnulls,
    short* __restrict__ Ob) {
    int gid = blockIdx.x * 256 + threadIdx.x;
    int i4 = gid * 4;                    // 64*512*64 floats total
    int row = i4 >> 6;                   // h*512 + (t-512)
    int d0 = i4 & 63;
    int h = row >> 9;
    int t = 512 + (row & 511);
    float sink = sinks[h];
    float inv = __builtin_amdgcn_rcpf(totf[row] + sink + 1e-6f);
    f32x4 o = *(const f32x4*)(Of + i4);
    s16x4 rs;
    #pragma unroll
    for (int k = 0; k < 4; ++k)
        rs[k] = f2b((o[k] + sink * vnulls[h * 64 + d0 + k]) * inv);
    *(s16x4*)(Ob + (size_t)t * 4096 + h * 64 + d0) = rs;
}

// ---------- launch ----------
extern "C" void kernel_launch(void* const* d_in, const int* in_sizes, int n_in,
                              void* d_out, int out_size, void* d_ws, size_t ws_size,
                              hipStream_t stream) {
    const float* X        = (const float*)d_in[0];
    const float* W_Q      = (const float*)d_in[1];
    const float* b_Q      = (const float*)d_in[2];
    const float* W_K      = (const float*)d_in[3];
    const float* b_K      = (const float*)d_in[4];
    const float* W_V      = (const float*)d_in[5];
    const float* b_V      = (const float*)d_in[6];
    const float* sinks    = (const float*)d_in[7];
    const float* v_nulls  = (const float*)d_in[8];
    const float* W_O      = (const float*)d_in[9];
    const float* W_O_bias = (const float*)d_in[10];
    float* out = (float*)d_out;
    char* ws = (char*)d_ws;

    short* Xb        = (short*)(ws + 0);          //  2 MB  (1024x1024)
    short* WbT       = (short*)(ws + 2097152);    // 12 MB  (6144x1024) — dead after QKV GEMM
    short* WoT       = (short*)(ws + 14680064);   //  8 MB  (1024x4096), pre-scaled 0.25
    short* QKVb      = (short*)(ws + 23068672);   // 12 MB  (1024x6144)
    short* Vtb       = (short*)(ws + 35651584);   //  2 MB  (16x64x1024)
    short* Ob        = (short*)(ws + 37748736);   //  8 MB  (1024x4096)
    float* ksr       = (float*)(ws + 46137344);   // 64 KB  (16x1024)
    float* biasQKV   = (float*)(ws + 46202880);   // 24 KB
    // Of/totf alias the (dead-by-then) WbT region: 8 MB + 128 KB
    float* Of        = (float*)(ws + 2097152);    // 64 heads x 512 rows x 64 d, fp32
    float* totf      = Of + 64 * 512 * 64;        // 64 x 512 fp32

    prep_kernel<<<3864, 256, 0, stream>>>(X, W_Q, W_K, W_V, W_O, b_Q, b_K, b_V, W_O_bias,
                                          Xb, WbT, WoT, biasQKV, out);
    gemm_qkv_kernel<<<dim3(48, 16), 256, 0, stream>>>(Xb, WbT, biasQKV, QKVb, 1024, 6144, 1024);
    rope_vt_kernel<<<1536, 256, 0, stream>>>(QKVb, ksr, Vtb);
    hipMemsetAsync(Of, 0, (size_t)(64 * 512 * 64 + 64 * 512) * sizeof(float), stream);
    attn_kernel<<<dim3(64, 24), 256, 0, stream>>>(QKVb, Vtb, ksr, sinks, v_nulls, Ob, Of, totf);
    norm_kernel<<<2048, 256, 0, stream>>>(Of, totf, sinks, v_nulls, Ob);
    gemm_op_kernel<<<dim3(8, 16, 8), 256, 0, stream>>>(Ob, WoT, out, 1024, 1024, 4096, 512);
}

// Round 7
// 184.383 us; speedup vs baseline: 2.2397x; 1.1104x over previous
//
#include <hip/hip_runtime.h>
#include <math.h>

// ---------- types ----------
typedef __attribute__((ext_vector_type(4))) float  f32x4;
typedef __attribute__((ext_vector_type(8))) short  bf16x8;   // 8 bf16 in 4 VGPRs
typedef __attribute__((ext_vector_type(4))) short  s16x4;

#define SQUISH_U 1.8137993642342178f      // pi/sqrt(3)  (applied to u = sp(z)/ln2)
#define LN2F     0.69314718055994531f

__device__ __forceinline__ float b2f(short u) {
    union { float f; unsigned b; } v; v.b = ((unsigned)(unsigned short)u) << 16; return v.f;
}
__device__ __forceinline__ short f2b(float f) {
    union { float f; unsigned b; } v; v.f = f;
    unsigned r = (v.b + 0x7FFFu + ((v.b >> 16) & 1u)) >> 16;   // RNE
    return (short)r;
}
__device__ __forceinline__ unsigned cvt_pk_bf16(float lo, float hi) {
    unsigned r;
    asm("v_cvt_pk_bf16_f32 %0, %1, %2" : "=v"(r) : "v"(lo), "v"(hi));
    return r;
}
// async global->LDS; lds base wave-uniform, HW adds lane*size
__device__ __forceinline__ void gll16(const void* g, void* l) {
    __builtin_amdgcn_global_load_lds((const __attribute__((address_space(1))) void*)g,
                                     (__attribute__((address_space(3))) void*)l, 16, 0, 0);
}
__device__ __forceinline__ void gll4(const void* g, void* l) {
    __builtin_amdgcn_global_load_lds((const __attribute__((address_space(1))) void*)g,
                                     (__attribute__((address_space(3))) void*)l, 4, 0, 0);
}

// ---------- unified prep kernel ----------
__device__ __forceinline__ void do_transpose(const float* __restrict__ src, int R, int C,
                                             short* __restrict__ dst, float scale,
                                             int c0, int r0, float (*tile)[65], int tid) {
    #pragma unroll
    for (int it = 0; it < 4; ++it) {
        int lin = it * 256 + tid;
        int r = lin >> 4, c4 = lin & 15;
        f32x4 v = *(const f32x4*)(src + (size_t)(r0 + r) * C + c0 + c4 * 4);
        #pragma unroll
        for (int k = 0; k < 4; ++k) tile[r][c4 * 4 + k] = v[k];
    }
    __syncthreads();
    #pragma unroll
    for (int it = 0; it < 4; ++it) {
        int lin = it * 256 + tid;
        int c = lin >> 4, rq = lin & 15;
        s16x4 o;
        #pragma unroll
        for (int k = 0; k < 4; ++k) o[k] = f2b(tile[rq * 4 + k][c] * scale);
        *(s16x4*)(dst + (size_t)(c0 + c) * R + r0 + rq * 4) = o;
    }
}

__global__ __launch_bounds__(256) void prep_kernel(
    const float* __restrict__ X, const float* __restrict__ W_Q, const float* __restrict__ W_K,
    const float* __restrict__ W_V, const float* __restrict__ W_O,
    const float* __restrict__ bQ, const float* __restrict__ bK, const float* __restrict__ bV,
    const float* __restrict__ bO,
    short* __restrict__ Xb, short* __restrict__ WbT, short* __restrict__ WoT,
    float* __restrict__ biasQKV, float* __restrict__ out) {
    __shared__ float tile[64][65];
    const int bid = blockIdx.x, tid = threadIdx.x;
    if (bid < 256) {
        int i = (bid * 256 + tid) * 16;
        #pragma unroll
        for (int k = 0; k < 4; ++k) {
            f32x4 v = *(const f32x4*)(X + i + k * 4);
            s16x4 o;
            o.x = f2b(v.x); o.y = f2b(v.y); o.z = f2b(v.z); o.w = f2b(v.w);
            *(s16x4*)(Xb + i + k * 4) = o;
        }
    } else if (bid < 1280) {
        int b2 = bid - 256;
        do_transpose(W_Q, 1024, 4096, WbT, 1.f, (b2 & 63) * 64, (b2 >> 6) * 64, tile, tid);
    } else if (bid < 1536) {
        int b2 = bid - 1280;
        do_transpose(W_K, 1024, 1024, WbT + 4096 * 1024, 1.f, (b2 & 15) * 64, (b2 >> 4) * 64, tile, tid);
    } else if (bid < 1792) {
        int b2 = bid - 1536;
        do_transpose(W_V, 1024, 1024, WbT + 5120 * 1024, 1.f, (b2 & 15) * 64, (b2 >> 4) * 64, tile, tid);
    } else if (bid < 2816) {
        int b2 = bid - 1792;
        do_transpose(W_O, 4096, 1024, WoT, 0.25f, (b2 & 15) * 64, (b2 >> 4) * 64, tile, tid);
    } else if (bid < 2840) {
        int i = (bid - 2816) * 256 + tid;
        if (i < 4096)      biasQKV[i] = bQ[i];
        else if (i < 5120) biasQKV[i] = bK[i - 4096];
        else               biasQKV[i] = bV[i - 5120];
    } else {
        int i = ((bid - 2840) * 256 + tid) * 4;
        f32x4 v;
        #pragma unroll
        for (int k = 0; k < 4; ++k) {
            int c = (i + k) & 1023;
            v[k] = 0.25f * (bO[c] + bO[1024 + c] + bO[2048 + c] + bO[3072 + c]);
        }
        *(f32x4*)(out + i) = v;
    }
}

// ---------- 64x128 GEMM core, dbuf counted-vmcnt ----------
#define GSTAGE_64x128(k0_, b_) do {                                            \
    _Pragma("unroll")                                                          \
    for (int it = 0; it < 2; ++it) {                                           \
        int lin0 = it * 256 + wave * 64;                                       \
        int lin = lin0 + lane;                                                 \
        int r = lin >> 3, c = (lin & 7) ^ (r & 7);                             \
        gll16(A + (size_t)(m0 + r) * K + (k0_) + c * 8, (char*)lA[b_] + lin0 * 16); \
    }                                                                          \
    _Pragma("unroll")                                                          \
    for (int it = 0; it < 4; ++it) {                                           \
        int lin0 = it * 256 + wave * 64;                                       \
        int lin = lin0 + lane;                                                 \
        int r = lin >> 3, c = (lin & 7) ^ (r & 7);                             \
        gll16(BT + (size_t)(n0 + r) * K + (k0_) + c * 8, (char*)lB[b_] + lin0 * 16); \
    } } while (0)

#define GEMM_CORE_64x128(kbeg_, kend_)                                         \
    GSTAGE_64x128(kbeg_, 0);                                                   \
    int cur = 0;                                                               \
    for (int k0 = (kbeg_); k0 < (kend_); k0 += 64) {                           \
        if (k0 + 64 < (kend_)) {                                               \
            GSTAGE_64x128(k0 + 64, cur ^ 1);                                   \
            asm volatile("s_waitcnt vmcnt(6) lgkmcnt(0)" ::: "memory");        \
        } else {                                                               \
            asm volatile("s_waitcnt vmcnt(0) lgkmcnt(0)" ::: "memory");        \
        }                                                                      \
        __builtin_amdgcn_s_barrier();                                          \
        _Pragma("unroll")                                                      \
        for (int kk = 0; kk < 2; ++kk) {                                       \
            bf16x8 af[2], bf_[4];                                              \
            _Pragma("unroll")                                                  \
            for (int m = 0; m < 2; ++m) {                                      \
                int row = wr * 32 + m * 16 + l15;                              \
                int ch = (kk * 4 + l4) ^ (row & 7);                            \
                af[m] = *(const bf16x8*)&lA[cur][row][ch << 3];                \
            }                                                                  \
            _Pragma("unroll")                                                  \
            for (int n = 0; n < 4; ++n) {                                      \
                int row = wc * 64 + n * 16 + l15;                              \
                int ch = (kk * 4 + l4) ^ (row & 7);                            \
                bf_[n] = *(const bf16x8*)&lB[cur][row][ch << 3];               \
            }                                                                  \
            _Pragma("unroll")                                                  \
            for (int m = 0; m < 2; ++m)                                        \
                _Pragma("unroll")                                              \
                for (int n = 0; n < 4; ++n)                                    \
                    acc[m][n] = __builtin_amdgcn_mfma_f32_16x16x32_bf16(af[m], bf_[n], acc[m][n], 0, 0, 0); \
        }                                                                      \
        asm volatile("" ::: "memory");                                         \
        __builtin_amdgcn_s_barrier();                                          \
        cur ^= 1;                                                              \
    }

// ---------- QKV GEMM with fused bias + RoPE + ksr + V-transpose ----------
// grid (48, 16). Each wave owns one head-slot (64 cols) x 32 rows:
// head = blockIdx.x*2 + wc; 0..63 = Q (rope), 64..79 = K (rope + ksr), 80..95 = V (-> Vtb).
__global__ __launch_bounds__(256, 3) void gemm_qkvf_kernel(
    const short* __restrict__ A, const short* __restrict__ BT,
    const float* __restrict__ bias, short* __restrict__ QKVb,
    short* __restrict__ Vtb, float* __restrict__ ksr,
    int M, int N, int K) {
    __shared__ short lA[2][64][64];
    __shared__ short lB[2][128][64];
    const int tid = threadIdx.x;
    const int lane = tid & 63, wave = tid >> 6;
    const int l15 = lane & 15, l4 = lane >> 4;
    const int wr = wave >> 1, wc = wave & 1;
    const int n0 = blockIdx.x * 128, m0 = blockIdx.y * 64;

    f32x4 acc[2][4];
    const f32x4 fz = {0.f, 0.f, 0.f, 0.f};
    #pragma unroll
    for (int m = 0; m < 2; ++m)
        #pragma unroll
        for (int n = 0; n < 4; ++n) acc[m][n] = fz;

    GEMM_CORE_64x128(0, K);

    const int head = blockIdx.x * 2 + wc;
    // bias (before rope, matching reference order)
    float bn[4];
    #pragma unroll
    for (int n = 0; n < 4; ++n) bn[n] = bias[head * 64 + n * 16 + l15];
    #pragma unroll
    for (int m = 0; m < 2; ++m)
        #pragma unroll
        for (int n = 0; n < 4; ++n)
            #pragma unroll
            for (int r = 0; r < 4; ++r) acc[m][n][r] += bn[n];

    if (head < 80) {
        // RoPE: out[j] = x1*cos - x2*sin, out[32+j] = x1*sin + x2*cos, (x1,x2)=(in[2j],in[2j+1])
        const float invf0 = __builtin_exp2f(-(float)l15 * 0.41524101186092033f); // 10000^(-l15/32)
        const float invf1 = invf0 * 0.01f;                                      // j+16 -> *10000^(-1/2)
        const int p1 = (2 * l15) & 15, p2 = (2 * l15 + 1) & 15;
        #pragma unroll
        for (int m = 0; m < 2; ++m) {
            int tb = m0 + wr * 32 + m * 16 + l4 * 4;
            float x1lo[4], x2lo[4], x1hi[4], x2hi[4];
            #pragma unroll
            for (int r = 0; r < 4; ++r) {
                float a0 = __shfl(acc[m][0][r], p1, 16), b0 = __shfl(acc[m][1][r], p1, 16);
                float a1 = __shfl(acc[m][0][r], p2, 16), b1 = __shfl(acc[m][1][r], p2, 16);
                x1lo[r] = (l15 < 8) ? a0 : b0;
                x2lo[r] = (l15 < 8) ? a1 : b1;
                float c0 = __shfl(acc[m][2][r], p1, 16), d0 = __shfl(acc[m][3][r], p1, 16);
                float c1 = __shfl(acc[m][2][r], p2, 16), d1 = __shfl(acc[m][3][r], p2, 16);
                x1hi[r] = (l15 < 8) ? c0 : d0;
                x2hi[r] = (l15 < 8) ? c1 : d1;
            }
            #pragma unroll
            for (int r = 0; r < 4; ++r) {
                float tf = (float)(tb + r);
                float f0 = tf * invf0, f1 = tf * invf1;
                float s0 = __sinf(f0), c0 = __cosf(f0);
                float s1 = __sinf(f1), c1 = __cosf(f1);
                acc[m][0][r] = x1lo[r] * c0 - x2lo[r] * s0;   // col l15      (j)
                acc[m][2][r] = x1lo[r] * s0 + x2lo[r] * c0;   // col 32+l15   (32+j)
                acc[m][1][r] = x1hi[r] * c1 - x2hi[r] * s1;   // col 16+l15   (j+16)
                acc[m][3][r] = x1hi[r] * s1 + x2hi[r] * c1;   // col 48+l15   (48+j)
            }
        }
    }

    if (head >= 80) {
        // V: write transposed straight to Vtb[h16*64+d][t]
        const int h16 = head - 80;
        #pragma unroll
        for (int m = 0; m < 2; ++m) {
            int tb = m0 + wr * 32 + m * 16 + l4 * 4;
            #pragma unroll
            for (int n = 0; n < 4; ++n) {
                s16x4 o;
                #pragma unroll
                for (int r = 0; r < 4; ++r) o[r] = f2b(acc[m][n][r]);
                *(s16x4*)(Vtb + (size_t)(h16 * 64 + n * 16 + l15) * 1024 + tb) = o;
            }
        }
    } else {
        const size_t coff = (head < 64) ? (size_t)head * 64 : (size_t)(4096 + (head - 64) * 64);
        #pragma unroll
        for (int m = 0; m < 2; ++m)
            #pragma unroll
            for (int r = 0; r < 4; ++r) {
                int row = m0 + wr * 32 + m * 16 + l4 * 4 + r;
                #pragma unroll
                for (int n = 0; n < 4; ++n)
                    QKVb[(size_t)row * 6144 + coff + n * 16 + l15] = f2b(acc[m][n][r]);
            }
        if (head >= 64) {
            const int h16 = head - 64;
            #pragma unroll
            for (int m = 0; m < 2; ++m)
                #pragma unroll
                for (int r = 0; r < 4; ++r) {
                    float ss = 0.f;
                    #pragma unroll
                    for (int n = 0; n < 4; ++n) ss += acc[m][n][r] * acc[m][n][r];
                    ss += __shfl_xor(ss, 1, 16);
                    ss += __shfl_xor(ss, 2, 16);
                    ss += __shfl_xor(ss, 4, 16);
                    ss += __shfl_xor(ss, 8, 16);
                    if (l15 == 0)
                        ksr[h16 * 1024 + m0 + wr * 32 + m * 16 + l4 * 4 + r] =
                            0.18033688011112042f * rsqrtf(fmaxf(ss, 1e-6f));   // log2e * 0.125 * rsqrt
                }
        }
    }
}

// ---------- out-proj: 64x128 tile, split-K=4, fp32 atomic accumulate ----------
__global__ __launch_bounds__(256, 3) void gemm_op_kernel(
    const short* __restrict__ A, const short* __restrict__ BT,
    float* __restrict__ out, int M, int N, int K, int KSLICE) {
    __shared__ short lA[2][64][64];
    __shared__ short lB[2][128][64];
    const int tid = threadIdx.x;
    const int lane = tid & 63, wave = tid >> 6;
    const int l15 = lane & 15, l4 = lane >> 4;
    const int wr = wave >> 1, wc = wave & 1;
    const int n0 = blockIdx.x * 128, m0 = blockIdx.y * 64;
    const int kbeg = blockIdx.z * KSLICE, kend = kbeg + KSLICE;

    f32x4 acc[2][4];
    const f32x4 fz = {0.f, 0.f, 0.f, 0.f};
    #pragma unroll
    for (int m = 0; m < 2; ++m)
        #pragma unroll
        for (int n = 0; n < 4; ++n) acc[m][n] = fz;

    GEMM_CORE_64x128(kbeg, kend);

    #pragma unroll
    for (int m = 0; m < 2; ++m)
        #pragma unroll
        for (int n = 0; n < 4; ++n)
            #pragma unroll
            for (int r = 0; r < 4; ++r) {
                int row = m0 + wr * 32 + m * 16 + l4 * 4 + r;
                int col = n0 + wc * 64 + n * 16 + l15;
                unsafeAtomicAdd(&out[(size_t)row * N + col], acc[m][n][r]);
            }
}

// ---------- attention, k-split for load balance + occupancy ----------
__constant__ __device__ const signed char TQT[24] = {15,15,14, 7,14,13,13,12, 6,12,11,11,10, 5,10, 9, 9, 8, 4, 8, 3, 2, 1, 0};
__constant__ __device__ const signed char TKB[24] = { 0, 8, 0, 0, 8, 0, 7, 0, 0, 7, 0, 6, 0, 0, 6, 0, 5, 0, 0, 5, 0, 0, 0, 0};
__constant__ __device__ const signed char TKE[24] = { 8,16, 8, 8,15, 7,14, 7, 7,13, 6,12, 6, 6,11, 5,10, 5, 5, 9, 4, 3, 2, 1};

__global__ __launch_bounds__(256, 6) void attn_kernel(
    const short* __restrict__ QKVb, const short* __restrict__ Vtb,
    const float* __restrict__ ksr, const float* __restrict__ sinks,
    const float* __restrict__ vnulls, short* __restrict__ Ob,
    float* __restrict__ Of0, float* __restrict__ Of1,
    float* __restrict__ tot0, float* __restrict__ tot1) {
    __shared__ short lK[64][64];
    __shared__ short lV[64][64];
    __shared__ float lks[64];
    __shared__ float lvn[64];
    __shared__ short lP[4][16][64];

    const int tid = threadIdx.x;
    const int lane = tid & 63, wave = tid >> 6;
    const int l15 = lane & 15, l4 = lane >> 4;
    const int h = blockIdx.x;
    const int slot = blockIdx.y;
    const int qt = TQT[slot], kb = TKB[slot], ke = TKE[slot];
    const bool single = (kb == 0) && (ke == qt + 1);
    const int h16 = h & 15;
    const int t0 = qt * 64;
    const float sink = sinks[h];
    if (tid < 64) lvn[tid] = vnulls[h * 64 + tid];

    const int q_abs = t0 + wave * 16 + l15;
    bf16x8 aq[2];
    #pragma unroll
    for (int kk = 0; kk < 2; ++kk)
        aq[kk] = *(const bf16x8*)(QKVb + (size_t)q_abs * 6144 + h * 64 + kk * 32 + l4 * 8);

    const f32x4 fz = {0.f, 0.f, 0.f, 0.f};
    f32x4 acc_o[4];
    #pragma unroll
    for (int n = 0; n < 4; ++n) acc_o[n] = fz;
    float tot = 0.f;

#define ASTAGE(s0_) do {                                                              \
    int lin0 = wave * 64;                                                             \
    int lin = lin0 + lane;                                                            \
    int r = lin >> 3, c = (lin & 7) ^ (r & 7);                                        \
    gll16(QKVb + (size_t)((s0_) + r) * 6144 + 4096 + h16 * 64 + c * 8, (char*)lK + lin0 * 16); \
    gll16(Vtb + (size_t)(h16 * 64 + r) * 1024 + (s0_) + c * 8,         (char*)lV + lin0 * 16); \
    lin0 += 256; lin = lin0 + lane; r = lin >> 3; c = (lin & 7) ^ (r & 7);            \
    gll16(QKVb + (size_t)((s0_) + r) * 6144 + 4096 + h16 * 64 + c * 8, (char*)lK + lin0 * 16); \
    gll16(Vtb + (size_t)(h16 * 64 + r) * 1024 + (s0_) + c * 8,         (char*)lV + lin0 * 16); \
    gll4(ksr + h16 * 1024 + (s0_) + lane, (char*)lks);                                \
} while (0)

    for (int kt = kb; kt < ke; ++kt) {
        int s0 = kt * 64;
        __syncthreads();
        ASTAGE(s0);
        asm volatile("s_waitcnt vmcnt(0)" ::: "memory");
        __syncthreads();

        f32x4 accs[4];
        #pragma unroll
        for (int n = 0; n < 4; ++n) accs[n] = fz;
        #pragma unroll
        for (int kk = 0; kk < 2; ++kk) {
            bf16x8 bk[4];
            #pragma unroll
            for (int n = 0; n < 4; ++n) {
                int row = n * 16 + l15;
                int ch = (kk * 4 + l4) ^ (row & 7);
                bk[n] = *(const bf16x8*)&lK[row][ch << 3];
            }
            #pragma unroll
            for (int n = 0; n < 4; ++n)
                accs[n] = __builtin_amdgcn_mfma_f32_16x16x32_bf16(bk[n], aq[kk], accs[n], 0, 0, 0);
        }

        #pragma unroll
        for (int n = 0; n < 4; ++n) {
            f32x4 ksv = *(const f32x4*)&lks[n * 16 + l4 * 4];
            float w4[4];
            #pragma unroll
            for (int r = 0; r < 4; ++r) {
                int k_abs = s0 + n * 16 + l4 * 4 + r;
                float zz = accs[n][r] * ksv[r];                       // z*log2e (ksr pre-scaled)
                float t = __builtin_amdgcn_exp2f(zz);
                float u = __builtin_amdgcn_logf(1.f + t);             // log2(1+e^z)
                u = (k_abs <= q_abs) ? u : 0.f;
                float g = __builtin_amdgcn_rcpf(1.f + __builtin_amdgcn_exp2f(-SQUISH_U * u));
                float w = LN2F * u * g;
                w = (w >= sink) ? w : 0.f;
                tot += w;
                w4[r] = w;
            }
            unsigned pa = cvt_pk_bf16(w4[0], w4[1]);
            unsigned pb = cvt_pk_bf16(w4[2], w4[3]);
            int ch = (2 * n + (l4 >> 1)) ^ (l15 & 7);
            uint2 val; val.x = pa; val.y = pb;
            *(uint2*)&lP[wave][l15][ch * 8 + (l4 & 1) * 4] = val;
        }

        #pragma unroll
        for (int kk = 0; kk < 2; ++kk) {
            bf16x8 ap = *(const bf16x8*)&lP[wave][l15][((kk * 4 + l4) ^ (l15 & 7)) << 3];
            bf16x8 bv[4];
            #pragma unroll
            for (int n = 0; n < 4; ++n) {
                int row = n * 16 + l15;
                int ch = (kk * 4 + l4) ^ (row & 7);
                bv[n] = *(const bf16x8*)&lV[row][ch << 3];
            }
            #pragma unroll
            for (int n = 0; n < 4; ++n)
                acc_o[n] = __builtin_amdgcn_mfma_f32_16x16x32_bf16(ap, bv[n], acc_o[n], 0, 0, 0);
        }
    }
#undef ASTAGE

    tot += __shfl_xor(tot, 16, 64);
    tot += __shfl_xor(tot, 32, 64);

    if (single) {
        float tq[4];
        #pragma unroll
        for (int r = 0; r < 4; ++r) tq[r] = __shfl(tot, l4 * 4 + r, 64);
        #pragma unroll
        for (int r = 0; r < 4; ++r) {
            float inv = __builtin_amdgcn_rcpf(tq[r] + sink + 1e-6f);
            int trow = t0 + wave * 16 + l4 * 4 + r;
            #pragma unroll
            for (int n = 0; n < 4; ++n) {
                int d = n * 16 + l15;
                float val = (acc_o[n][r] + sink * lvn[d]) * inv;
                Ob[(size_t)trow * 4096 + h * 64 + d] = f2b(val);
            }
        }
    } else {
        // split rows (qt>=8): two blocks per row, each writes its own partial buffer (no init/atomics)
        float* Op = (kb == 0) ? Of0 : Of1;
        float* tp = (kb == 0) ? tot0 : tot1;
        if (lane < 16) tp[h * 512 + (t0 - 512) + wave * 16 + l15] = tot;
        #pragma unroll
        for (int r = 0; r < 4; ++r) {
            int pr = h * 512 + (t0 - 512) + wave * 16 + l4 * 4 + r;
            #pragma unroll
            for (int n = 0; n < 4; ++n)
                Op[(size_t)pr * 64 + n * 16 + l15] = acc_o[n][r];
        }
    }
}

// ---------- finalize split rows ----------
__global__ __launch_bounds__(256) void norm_kernel(
    const float* __restrict__ Of0, const float* __restrict__ Of1,
    const float* __restrict__ tot0, const float* __restrict__ tot1,
    const float* __restrict__ sinks, const float* __restrict__ vnulls,
    short* __restrict__ Ob) {
    int gid = blockIdx.x * 256 + threadIdx.x;
    int i4 = gid * 4;
    int row = i4 >> 6;                   // h*512 + (t-512)
    int d0 = i4 & 63;
    int h = row >> 9;
    int t = 512 + (row & 511);
    float sink = sinks[h];
    float inv = __builtin_amdgcn_rcpf(tot0[row] + tot1[row] + sink + 1e-6f);
    f32x4 a = *(const f32x4*)(Of0 + i4);
    f32x4 b = *(const f32x4*)(Of1 + i4);
    s16x4 rs;
    #pragma unroll
    for (int k = 0; k < 4; ++k)
        rs[k] = f2b((a[k] + b[k] + sink * vnulls[h * 64 + d0 + k]) * inv);
    *(s16x4*)(Ob + (size_t)t * 4096 + h * 64 + d0) = rs;
}

// ---------- launch ----------
extern "C" void kernel_launch(void* const* d_in, const int* in_sizes, int n_in,
                              void* d_out, int out_size, void* d_ws, size_t ws_size,
                              hipStream_t stream) {
    const float* X        = (const float*)d_in[0];
    const float* W_Q      = (const float*)d_in[1];
    const float* b_Q      = (const float*)d_in[2];
    const float* W_K      = (const float*)d_in[3];
    const float* b_K      = (const float*)d_in[4];
    const float* W_V      = (const float*)d_in[5];
    const float* b_V      = (const float*)d_in[6];
    const float* sinks    = (const float*)d_in[7];
    const float* v_nulls  = (const float*)d_in[8];
    const float* W_O      = (const float*)d_in[9];
    const float* W_O_bias = (const float*)d_in[10];
    float* out = (float*)d_out;
    char* ws = (char*)d_ws;

    short* Xb        = (short*)(ws + 0);          //  2 MB
    short* WbT       = (short*)(ws + 2097152);    // 12 MB
    short* WoT       = (short*)(ws + 14680064);   //  8 MB (x0.25)
    short* QKVb      = (short*)(ws + 23068672);   // 12 MB (V region unused)
    short* Vtb       = (short*)(ws + 35651584);   //  2 MB
    short* Ob        = (short*)(ws + 37748736);   //  8 MB
    float* ksr       = (float*)(ws + 46137344);   // 64 KB
    float* biasQKV   = (float*)(ws + 46202880);   // 24 KB
    float* Of0       = (float*)(ws + 50331648);   //  8.4 MB
    float* Of1       = (float*)(ws + 58720256);   //  8.4 MB
    float* tot0      = (float*)(ws + 67108864);   // 128 KB
    float* tot1      = (float*)(ws + 67239936);   // 128 KB

    prep_kernel<<<3864, 256, 0, stream>>>(X, W_Q, W_K, W_V, W_O, b_Q, b_K, b_V, W_O_bias,
                                          Xb, WbT, WoT, biasQKV, out);
    gemm_qkvf_kernel<<<dim3(48, 16), 256, 0, stream>>>(Xb, WbT, biasQKV, QKVb, Vtb, ksr,
                                                       1024, 6144, 1024);
    attn_kernel<<<dim3(64, 24), 256, 0, stream>>>(QKVb, Vtb, ksr, sinks, v_nulls, Ob,
                                                  Of0, Of1, tot0, tot1);
    norm_kernel<<<2048, 256, 0, stream>>>(Of0, Of1, tot0, tot1, sinks, v_nulls, Ob);
    gemm_op_kernel<<<dim3(8, 16, 4), 256, 0, stream>>>(Ob, WoT, out, 1024, 1024, 4096, 1024);
}